// Round 4
// baseline (593.465 us; speedup 1.0000x reference)
//
#include <hip/hip_runtime.h>
#include <hip/hip_bf16.h>

#define BATCH 2
#define SEQ   2048
#define HID   2048
#define NH    16
#define NKV   8
#define HD    128

typedef __bf16 bf16;
typedef bf16  bf16x8  __attribute__((ext_vector_type(8)));
typedef bf16  bf16x4  __attribute__((ext_vector_type(4)));
typedef float floatx4 __attribute__((ext_vector_type(4)));

typedef __attribute__((address_space(3))) void lds_void;
typedef const __attribute__((address_space(1))) void gmem_void;

__device__ inline void async16(const void* g, void* l) {
    __builtin_amdgcn_global_load_lds((gmem_void*)g, (lds_void*)l, 16, 0, 0);
}

// workspace layout constants (elements)
#define XN  8388608u
#define QWN 4194304u
#define KWN 2097152u
#define VWN 2097152u
#define OWN 4194304u

// ---------------------------------------------------------------------------
// f32 -> bf16 bulk convert (memory-bound)
// ---------------------------------------------------------------------------
__global__ __launch_bounds__(256) void cvt(bf16* __restrict__ dst,
                                           const float* __restrict__ src, int n)
{
    int i = (blockIdx.x * 256 + threadIdx.x) * 8;
    if (i >= n) return;
    const float4* p = (const float4*)(src + i);
    float4 u0 = p[0], u1 = p[1];
    bf16x8 v;
    v[0] = (bf16)u0.x; v[1] = (bf16)u0.y; v[2] = (bf16)u0.z; v[3] = (bf16)u0.w;
    v[4] = (bf16)u1.x; v[5] = (bf16)u1.y; v[6] = (bf16)u1.z; v[7] = (bf16)u1.w;
    *(bf16x8*)(dst + i) = v;
}

// ---------------------------------------------------------------------------
// GEMM  C = A[M,K] * W[N,K]^T, 128x128 tile, BK=32, m97 structure.
// AMODE: 0 = A f32 row-major (manual cvt stage)
//        1 = A bf16 row-major (global_load_lds)
//        2 = A bf16 head-major [B][K/128][2048][128] (global_load_lds)
// WMODE: 0 = W f32 (manual cvt)   1 = W bf16 (global_load_lds)
// CMODE: 0 = C f32 row-major      1 = C bf16 head-major [B][N/128][2048][128]
//        2 = C bf16 transposed    [B][N][2048]   (V^T)
//        3 = fused QKV epilogue: Cp = qb base; kb/vt at fixed ws offsets.
//            n<2048 -> q head-major; n<3072 -> k head-major; else v^T.
// ---------------------------------------------------------------------------
template <int AMODE, int WMODE, int CMODE>
__global__ __launch_bounds__(256) void gemm128(void* __restrict__ Cp,
                                               const void* __restrict__ Ap,
                                               const void* __restrict__ Wp,
                                               int M, int N, int K)
{
    __shared__ bf16 As[128 * 32];
    __shared__ bf16 Ws[128 * 32];

    const int tid  = threadIdx.x;
    const int wv   = tid >> 6;
    const int lane = tid & 63;
    const int quad = lane >> 4;
    const int c    = lane & 15;

    const int m0 = blockIdx.x * 128;
    const int n0 = blockIdx.y * 128;
    const int wm = (wv >> 1) * 64;
    const int wn = (wv & 1) * 64;

    const int arow = lane >> 2;        // async: row within 16-row chunk
    const int acol = (lane & 3) * 8;   // async: elem offset in BK

    floatx4 acc[4][4] = {};

    for (int k0 = 0; k0 < K; k0 += 32) {
        // ---- stage A tile (128 x 32) ----
        if constexpr (AMODE == 0) {
            const float* A = (const float*)Ap;
            #pragma unroll
            for (int it = 0; it < 2; it++) {
                int row = it * 64 + (tid >> 2);
                int col = (tid & 3) * 8;
                const float4* p = (const float4*)(A + (size_t)(m0 + row) * K + k0 + col);
                float4 u0 = p[0], u1 = p[1];
                bf16x8 v;
                v[0] = (bf16)u0.x; v[1] = (bf16)u0.y; v[2] = (bf16)u0.z; v[3] = (bf16)u0.w;
                v[4] = (bf16)u1.x; v[5] = (bf16)u1.y; v[6] = (bf16)u1.z; v[7] = (bf16)u1.w;
                *(bf16x8*)(&As[row * 32 + col]) = v;
            }
        } else {
            const bf16* A = (const bf16*)Ap;
            #pragma unroll
            for (int ch = 0; ch < 2; ch++) {
                int row = wv * 32 + ch * 16 + arow;
                const bf16* g;
                if constexpr (AMODE == 1) {
                    g = A + (size_t)(m0 + row) * K + k0 + acol;
                } else {   // head-major: [B][K>>7][2048][128]
                    int m = m0 + row;
                    g = A + (((size_t)(m >> 11) * (K >> 7) + (k0 >> 7)) * 2048 + (m & 2047)) * 128
                          + (k0 & 127) + acol;
                }
                async16(g, &As[(wv * 32 + ch * 16) * 32]);
            }
        }
        // ---- stage W tile (128 x 32) ----
        if constexpr (WMODE == 0) {
            const float* W = (const float*)Wp;
            #pragma unroll
            for (int it = 0; it < 2; it++) {
                int row = it * 64 + (tid >> 2);
                int col = (tid & 3) * 8;
                const float4* p = (const float4*)(W + (size_t)(n0 + row) * K + k0 + col);
                float4 u0 = p[0], u1 = p[1];
                bf16x8 v;
                v[0] = (bf16)u0.x; v[1] = (bf16)u0.y; v[2] = (bf16)u0.z; v[3] = (bf16)u0.w;
                v[4] = (bf16)u1.x; v[5] = (bf16)u1.y; v[6] = (bf16)u1.z; v[7] = (bf16)u1.w;
                *(bf16x8*)(&Ws[row * 32 + col]) = v;
            }
        } else {
            const bf16* W = (const bf16*)Wp;
            #pragma unroll
            for (int ch = 0; ch < 2; ch++) {
                int row = wv * 32 + ch * 16 + arow;
                const bf16* g = W + (size_t)(n0 + row) * K + k0 + acol;
                async16(g, &Ws[(wv * 32 + ch * 16) * 32]);
            }
        }
        __syncthreads();

        bf16x8 af[4], bw[4];
        #pragma unroll
        for (int i = 0; i < 4; i++) af[i] = *(const bf16x8*)(&As[(wm + i * 16 + c) * 32 + quad * 8]);
        #pragma unroll
        for (int j = 0; j < 4; j++) bw[j] = *(const bf16x8*)(&Ws[(wn + j * 16 + c) * 32 + quad * 8]);
        #pragma unroll
        for (int i = 0; i < 4; i++)
            #pragma unroll
            for (int j = 0; j < 4; j++)
                acc[i][j] = __builtin_amdgcn_mfma_f32_16x16x32_bf16(af[i], bw[j], acc[i][j], 0, 0, 0);
        __syncthreads();
    }

    // ---- epilogue.  C/D layout: col = lane&15, row = quad*4+reg ----
    if constexpr (CMODE == 0) {
        float* C = (float*)Cp;
        #pragma unroll
        for (int i = 0; i < 4; i++)
            #pragma unroll
            for (int j = 0; j < 4; j++)
                #pragma unroll
                for (int r = 0; r < 4; r++) {
                    int m = m0 + wm + i * 16 + quad * 4 + r;
                    int n = n0 + wn + j * 16 + c;
                    C[(size_t)m * N + n] = acc[i][j][r];
                }
    } else if constexpr (CMODE == 1) {
        bf16* C = (bf16*)Cp;
        const int b = m0 >> 11;
        #pragma unroll
        for (int j = 0; j < 4; j++) {
            int n = n0 + wn + j * 16 + c;
            size_t base = ((size_t)(b * (N >> 7) + (n >> 7)) * 2048) * 128 + (n & 127);
            #pragma unroll
            for (int i = 0; i < 4; i++)
                #pragma unroll
                for (int r = 0; r < 4; r++) {
                    int s = (m0 & 2047) + wm + i * 16 + quad * 4 + r;
                    C[base + (size_t)s * 128] = (bf16)acc[i][j][r];
                }
        }
    } else if constexpr (CMODE == 2) {   // V^T  [B][N][2048]
        bf16* C = (bf16*)Cp;
        const int b = m0 >> 11;
        #pragma unroll
        for (int j = 0; j < 4; j++) {
            int n = n0 + wn + j * 16 + c;
            size_t base = ((size_t)b * N + n) * 2048;
            #pragma unroll
            for (int i = 0; i < 4; i++) {
                int s0 = (m0 & 2047) + wm + i * 16 + quad * 4;
                bf16x4 v;
                #pragma unroll
                for (int r = 0; r < 4; r++) v[r] = (bf16)acc[i][j][r];
                *(bf16x4*)(&C[base + s0]) = v;
            }
        }
    } else {   // CMODE 3: fused QKV
        bf16* Cq = (bf16*)Cp;
        const int b = m0 >> 11;
        if (n0 < 2048) {
            #pragma unroll
            for (int j = 0; j < 4; j++) {
                int n = n0 + wn + j * 16 + c;
                size_t base = ((size_t)(b * 16 + (n >> 7)) * 2048) * 128 + (n & 127);
                #pragma unroll
                for (int i = 0; i < 4; i++)
                    #pragma unroll
                    for (int r = 0; r < 4; r++) {
                        int s = (m0 & 2047) + wm + i * 16 + quad * 4 + r;
                        Cq[base + (size_t)s * 128] = (bf16)acc[i][j][r];
                    }
            }
        } else if (n0 < 3072) {
            bf16* Ck = Cq + XN;
            #pragma unroll
            for (int j = 0; j < 4; j++) {
                int n = n0 - 2048 + wn + j * 16 + c;
                size_t base = ((size_t)(b * 8 + (n >> 7)) * 2048) * 128 + (n & 127);
                #pragma unroll
                for (int i = 0; i < 4; i++)
                    #pragma unroll
                    for (int r = 0; r < 4; r++) {
                        int s = (m0 & 2047) + wm + i * 16 + quad * 4 + r;
                        Ck[base + (size_t)s * 128] = (bf16)acc[i][j][r];
                    }
            }
        } else {
            bf16* Cv = Cq + XN + QWN;
            #pragma unroll
            for (int j = 0; j < 4; j++) {
                int n = n0 - 3072 + wn + j * 16 + c;
                size_t base = ((size_t)b * 1024 + n) * 2048;
                #pragma unroll
                for (int i = 0; i < 4; i++) {
                    int s0 = (m0 & 2047) + wm + i * 16 + quad * 4;
                    bf16x4 v;
                    #pragma unroll
                    for (int r = 0; r < 4; r++) v[r] = (bf16)acc[i][j][r];
                    *(bf16x4*)(&Cv[base + s0]) = v;
                }
            }
        }
    }
}

// ---------------------------------------------------------------------------
// RMSNorm(D=128) + RoPE, in place on head-major bf16 q/k.
// ---------------------------------------------------------------------------
__global__ __launch_bounds__(128) void norm_rope(bf16* __restrict__ q,
                                                 bf16* __restrict__ k,
                                                 const float* __restrict__ pe,
                                                 const float* __restrict__ qnw,
                                                 const float* __restrict__ knw)
{
    const int s  = blockIdx.x;
    const int hh = blockIdx.y;
    const int b  = blockIdx.z;
    const int d  = threadIdx.x;

    bf16* buf;
    const float* w;
    if (hh < NH) {
        buf = q + ((size_t)(b * NH + hh) * SEQ + s) * HD;
        w = qnw;
    } else {
        buf = k + ((size_t)(b * NKV + (hh - NH)) * SEQ + s) * HD;
        w = knw;
    }

    float x = (float)buf[d];
    float ss = x * x;
    #pragma unroll
    for (int m = 32; m; m >>= 1) ss += __shfl_xor(ss, m);

    __shared__ float red[2];
    __shared__ float nv[128];
    if ((d & 63) == 0) red[d >> 6] = ss;
    __syncthreads();
    float var = (red[0] + red[1]) * (1.0f / 128.0f);
    float nx = x * rsqrtf(var + 1e-6f) * w[d];
    nv[d] = nx;
    __syncthreads();

    const float* pev = pe + ((size_t)b * SEQ + s) * HD;
    float o;
    if (d < 64) {
        o = nx * pev[d] - nv[d + 64] * pev[64 + d];
    } else {
        o = nv[d - 64] * pev[d] + nx * pev[d - 64];
    }
    buf[d] = (bf16)o;
}

// ---------------------------------------------------------------------------
// Flash attention, causal, GQA rep=2.  128-row q-tile per block; each wave
// owns 2x16 q-rows (u=0: rows qw0.., u=1: rows qw0+64..), K/V fragments
// reused across u.  Static-max softmax: scores bounded by Cauchy-Schwarz
// (RMS=1 rows, norm-preserving RoPE) => |score*scale| <= ~11.36; use M=11.5.
// No in-loop reductions; l reduced once in epilogue.
// ---------------------------------------------------------------------------
__global__ __launch_bounds__(256) void fattn(bf16* __restrict__ O,
                                             const bf16* __restrict__ Q,
                                             const bf16* __restrict__ Kh,
                                             const bf16* __restrict__ Vtg)
{
    const int qblk = (int)gridDim.x - 1 - (int)blockIdx.x;   // heavy first
    const int h    = blockIdx.y;
    const int b    = blockIdx.z;
    const int kv   = h >> 1;

    const int tid  = threadIdx.x;
    const int wv   = tid >> 6;
    const int lane = tid & 63;
    const int quad = lane >> 4;
    const int c    = lane & 15;

    __shared__ bf16 Ks[64 * 136];        // [key][d]
    __shared__ bf16 Vs[128 * 72];        // [d][key]
    __shared__ bf16 Ps[8 * 16 * 72];     // per (wave,u) P tile

    const int qw0 = qblk * 128 + wv * 16;
    const int qw1 = qw0 + 64;

    bf16x8 qf[2][4];
    #pragma unroll
    for (int u = 0; u < 2; u++) {
        const bf16* qp = Q + ((size_t)(b * NH + h) * SEQ + (u ? qw1 : qw0) + c) * HD + quad * 8;
        #pragma unroll
        for (int t = 0; t < 4; t++) qf[u][t] = *(const bf16x8*)(qp + t * 32);
    }

    floatx4 o_acc[2][8] = {};
    float l_part[2][4] = {};

    const bf16* kbase = Kh  + (size_t)(b * NKV + kv) * SEQ * HD;
    const bf16* vbase = Vtg + (size_t)(b * NKV + kv) * HD * SEQ;

    const int kr  = tid >> 2, ksc = (tid & 3) * 32;   // K staging
    const int vd  = tid >> 1, vkc = (tid & 1) * 32;   // V^T staging
    bf16* psw0 = &Ps[(wv * 2 + 0) * 16 * 72];
    bf16* psw1 = &Ps[(wv * 2 + 1) * 16 * 72];
    const int nkt = qblk * 2 + 2;
    const float kS = 0.08838834764831845f * 1.4426950408889634f;  // scale*log2e
    const float kB = 11.5f * 1.4426950408889634f;                 // M*log2e

    for (int kt = 0; kt < nkt; kt++) {
        const int k0 = kt * 64;
        // ---- stage K[64][128] and V^T[128][64] ----
        {
            const bf16* kp = kbase + (size_t)(k0 + kr) * HD + ksc;
            #pragma unroll
            for (int i = 0; i < 4; i++)
                *(bf16x8*)(&Ks[kr * 136 + ksc + i * 8]) = *(const bf16x8*)(kp + i * 8);
            const bf16* vp = vbase + (size_t)vd * SEQ + k0 + vkc;
            #pragma unroll
            for (int i = 0; i < 4; i++)
                *(bf16x8*)(&Vs[vd * 72 + vkc + i * 8]) = *(const bf16x8*)(vp + i * 8);
        }
        __syncthreads();

        const bool act0 = (k0 <= qw0 + 15);   // wave-uniform

        // ---- QK^T, K fragments shared across u ----
        floatx4 sc0[4] = {}, sc1[4] = {};
        #pragma unroll
        for (int t = 0; t < 4; t++) {
            #pragma unroll
            for (int g = 0; g < 4; g++) {
                bf16x8 kf = *(const bf16x8*)(&Ks[(g * 16 + c) * 136 + t * 32 + quad * 8]);
                sc1[g] = __builtin_amdgcn_mfma_f32_16x16x32_bf16(qf[1][t], kf, sc1[g], 0, 0, 0);
                if (act0)
                    sc0[g] = __builtin_amdgcn_mfma_f32_16x16x32_bf16(qf[0][t], kf, sc0[g], 0, 0, 0);
            }
        }

        // ---- static-max softmax + P store (no reductions) ----
        #pragma unroll
        for (int r = 0; r < 4; r++) {
            const int qrow1 = qw1 + quad * 4 + r;
            #pragma unroll
            for (int g = 0; g < 4; g++) {
                float p = exp2f(sc1[g][r] * kS - kB);
                if (k0 + g * 16 + c > qrow1) p = 0.0f;
                l_part[1][r] += p;
                psw1[(quad * 4 + r) * 72 + g * 16 + c] = (bf16)p;
            }
        }
        if (act0) {
            #pragma unroll
            for (int r = 0; r < 4; r++) {
                const int qrow0 = qw0 + quad * 4 + r;
                #pragma unroll
                for (int g = 0; g < 4; g++) {
                    float p = exp2f(sc0[g][r] * kS - kB);
                    if (k0 + g * 16 + c > qrow0) p = 0.0f;
                    l_part[0][r] += p;
                    psw0[(quad * 4 + r) * 72 + g * 16 + c] = (bf16)p;
                }
            }
        }
        // drain ds_writes before wave-local ds_reads
        asm volatile("s_waitcnt lgkmcnt(0)" ::: "memory");

        bf16x8 p10 = *(const bf16x8*)(&psw1[c * 72 + quad * 8]);
        bf16x8 p11 = *(const bf16x8*)(&psw1[c * 72 + 32 + quad * 8]);
        bf16x8 p00, p01;
        if (act0) {
            p00 = *(const bf16x8*)(&psw0[c * 72 + quad * 8]);
            p01 = *(const bf16x8*)(&psw0[c * 72 + 32 + quad * 8]);
        }

        // ---- PV, V fragments shared across u ----
        #pragma unroll
        for (int f = 0; f < 8; f++) {
            bf16x8 vf0 = *(const bf16x8*)(&Vs[(f * 16 + c) * 72 + quad * 8]);
            bf16x8 vf1 = *(const bf16x8*)(&Vs[(f * 16 + c) * 72 + 32 + quad * 8]);
            o_acc[1][f] = __builtin_amdgcn_mfma_f32_16x16x32_bf16(p10, vf0, o_acc[1][f], 0, 0, 0);
            o_acc[1][f] = __builtin_amdgcn_mfma_f32_16x16x32_bf16(p11, vf1, o_acc[1][f], 0, 0, 0);
            if (act0) {
                o_acc[0][f] = __builtin_amdgcn_mfma_f32_16x16x32_bf16(p00, vf0, o_acc[0][f], 0, 0, 0);
                o_acc[0][f] = __builtin_amdgcn_mfma_f32_16x16x32_bf16(p01, vf1, o_acc[0][f], 0, 0, 0);
            }
        }
        __syncthreads();
    }

    // ---- epilogue: one l-reduction per row, normalize, store ----
    #pragma unroll
    for (int u = 0; u < 2; u++) {
        const int qwu = u ? qw1 : qw0;
        #pragma unroll
        for (int r = 0; r < 4; r++) {
            float l = l_part[u][r];
            #pragma unroll
            for (int msk = 8; msk; msk >>= 1) l += __shfl_xor(l, msk);
            const float inv = 1.0f / l;
            bf16* op = O + ((size_t)(b * NH + h) * SEQ + qwu + quad * 4 + r) * HD;
            #pragma unroll
            for (int f = 0; f < 8; f++) op[f * 16 + c] = (bf16)(o_acc[u][f][r] * inv);
        }
    }
}

// ---------------------------------------------------------------------------
extern "C" void kernel_launch(void* const* d_in, const int* in_sizes, int n_in,
                              void* d_out, int out_size, void* d_ws, size_t ws_size,
                              hipStream_t stream)
{
    const float* x   = (const float*)d_in[0];
    const float* pe  = (const float*)d_in[1];
    const float* qw  = (const float*)d_in[2];
    const float* kw  = (const float*)d_in[3];
    const float* vw  = (const float*)d_in[4];
    const float* ow  = (const float*)d_in[5];
    const float* qnw = (const float*)d_in[6];
    const float* knw = (const float*)d_in[7];
    float* out = (float*)d_out;

    bf16* qb = (bf16*)d_ws;          // [B][NH][S][HD]   head-major
    bf16* kb = qb + XN;              // [B][NKV][S][HD]  head-major
    bf16* vt = kb + KWN * 2;         // [B][NKV][HD][S]  V^T
    bf16* ab = vt + VWN * 2;         // [B][NH][S][HD]   head-major
    bf16* cvt_base = ab + XN;

    const bool fit = ws_size >= (size_t)92274688;
    const int M = BATCH * SEQ;

    if (fit) {
        bf16* xb  = cvt_base;
        bf16* qwb = xb  + XN;     // qwb|kwb|vwb contiguous => fused QKV weight [4096][2048]
        bf16* kwb = qwb + QWN;
        bf16* vwb = kwb + KWN;
        bf16* owb = vwb + VWN;
        cvt<<<XN  / 8 / 256, 256, 0, stream>>>(xb,  x,  (int)XN);
        cvt<<<QWN / 8 / 256, 256, 0, stream>>>(qwb, qw, (int)QWN);
        cvt<<<KWN / 8 / 256, 256, 0, stream>>>(kwb, kw, (int)KWN);
        cvt<<<VWN / 8 / 256, 256, 0, stream>>>(vwb, vw, (int)VWN);
        cvt<<<OWN / 8 / 256, 256, 0, stream>>>(owb, ow, (int)OWN);

        // fused Q|K|V projection: N = 2048+1024+1024, 1024 blocks
        gemm128<1, 1, 3><<<dim3(32, 32), 256, 0, stream>>>(qb, xb, qwb, M, 4096, 2048);

        norm_rope<<<dim3(SEQ, NH + NKV, BATCH), 128, 0, stream>>>(qb, kb, pe, qnw, knw);
        fattn<<<dim3(SEQ / 128, NH, BATCH), 256, 0, stream>>>(ab, qb, kb, vt);

        gemm128<2, 1, 0><<<dim3(32, 16), 256, 0, stream>>>(out, ab, owb, M, 2048, 2048);
    } else {
        gemm128<0, 0, 1><<<dim3(32, 16), 256, 0, stream>>>(qb, x, qw, M, 2048, 2048);
        gemm128<0, 0, 1><<<dim3(32,  8), 256, 0, stream>>>(kb, x, kw, M, 1024, 2048);
        gemm128<0, 0, 2><<<dim3(32,  8), 256, 0, stream>>>(vt, x, vw, M, 1024, 2048);

        norm_rope<<<dim3(SEQ, NH + NKV, BATCH), 128, 0, stream>>>(qb, kb, pe, qnw, knw);
        fattn<<<dim3(SEQ / 128, NH, BATCH), 256, 0, stream>>>(ab, qb, kb, vt);

        gemm128<2, 0, 0><<<dim3(32, 16), 256, 0, stream>>>(out, ab, ow, M, 2048, 2048);
    }
}

// Round 5
// 467.295 us; speedup vs baseline: 1.2700x; 1.2700x over previous
//
#include <hip/hip_runtime.h>
#include <hip/hip_bf16.h>

#define BATCH 2
#define SEQ   2048
#define HID   2048
#define NH    16
#define NKV   8
#define HD    128

typedef __bf16 bf16;
typedef bf16  bf16x8  __attribute__((ext_vector_type(8)));
typedef bf16  bf16x4  __attribute__((ext_vector_type(4)));
typedef float floatx4 __attribute__((ext_vector_type(4)));

typedef __attribute__((address_space(3))) void lds_void;
typedef const __attribute__((address_space(1))) void gmem_void;

__device__ inline void async16(const void* g, void* l) {
    __builtin_amdgcn_global_load_lds((gmem_void*)g, (lds_void*)l, 16, 0, 0);
}

// workspace layout constants (elements)
#define XN  8388608u
#define QWN 4194304u
#define KWN 2097152u
#define VWN 2097152u
#define OWN 4194304u

// ---------------------------------------------------------------------------
// f32 -> bf16 bulk convert (memory-bound)
// ---------------------------------------------------------------------------
__global__ __launch_bounds__(256) void cvt(bf16* __restrict__ dst,
                                           const float* __restrict__ src, int n)
{
    int i = (blockIdx.x * 256 + threadIdx.x) * 8;
    if (i >= n) return;
    const float4* p = (const float4*)(src + i);
    float4 u0 = p[0], u1 = p[1];
    bf16x8 v;
    v[0] = (bf16)u0.x; v[1] = (bf16)u0.y; v[2] = (bf16)u0.z; v[3] = (bf16)u0.w;
    v[4] = (bf16)u1.x; v[5] = (bf16)u1.y; v[6] = (bf16)u1.z; v[7] = (bf16)u1.w;
    *(bf16x8*)(dst + i) = v;
}

// ---------------------------------------------------------------------------
// GEMM  C = A[M,K] * W[N,K]^T, 128x128 tile, BK=32, m97 structure.
// AMODE: 0 = A f32 row-major (manual cvt stage)
//        1 = A bf16 row-major (global_load_lds)
//        2 = A bf16 head-major [B][K/128][2048][128] (global_load_lds)
// WMODE: 0 = W f32 (manual cvt)   1 = W bf16 (global_load_lds)
// CMODE: 0 = C f32 row-major      1 = C bf16 head-major [B][N/128][2048][128]
//        2 = C bf16 transposed    [B][N][2048]   (V^T)
//        3 = fused QKV epilogue: Cp = qb base; kb/vt at fixed ws offsets.
// ---------------------------------------------------------------------------
template <int AMODE, int WMODE, int CMODE>
__global__ __launch_bounds__(256) void gemm128(void* __restrict__ Cp,
                                               const void* __restrict__ Ap,
                                               const void* __restrict__ Wp,
                                               int M, int N, int K)
{
    __shared__ bf16 As[128 * 32];
    __shared__ bf16 Ws[128 * 32];

    const int tid  = threadIdx.x;
    const int wv   = tid >> 6;
    const int lane = tid & 63;
    const int quad = lane >> 4;
    const int c    = lane & 15;

    const int m0 = blockIdx.x * 128;
    const int n0 = blockIdx.y * 128;
    const int wm = (wv >> 1) * 64;
    const int wn = (wv & 1) * 64;

    const int arow = lane >> 2;
    const int acol = (lane & 3) * 8;

    floatx4 acc[4][4] = {};

    for (int k0 = 0; k0 < K; k0 += 32) {
        if constexpr (AMODE == 0) {
            const float* A = (const float*)Ap;
            #pragma unroll
            for (int it = 0; it < 2; it++) {
                int row = it * 64 + (tid >> 2);
                int col = (tid & 3) * 8;
                const float4* p = (const float4*)(A + (size_t)(m0 + row) * K + k0 + col);
                float4 u0 = p[0], u1 = p[1];
                bf16x8 v;
                v[0] = (bf16)u0.x; v[1] = (bf16)u0.y; v[2] = (bf16)u0.z; v[3] = (bf16)u0.w;
                v[4] = (bf16)u1.x; v[5] = (bf16)u1.y; v[6] = (bf16)u1.z; v[7] = (bf16)u1.w;
                *(bf16x8*)(&As[row * 32 + col]) = v;
            }
        } else {
            const bf16* A = (const bf16*)Ap;
            #pragma unroll
            for (int ch = 0; ch < 2; ch++) {
                int row = wv * 32 + ch * 16 + arow;
                const bf16* g;
                if constexpr (AMODE == 1) {
                    g = A + (size_t)(m0 + row) * K + k0 + acol;
                } else {   // head-major: [B][K>>7][2048][128]
                    int m = m0 + row;
                    g = A + (((size_t)(m >> 11) * (K >> 7) + (k0 >> 7)) * 2048 + (m & 2047)) * 128
                          + (k0 & 127) + acol;
                }
                async16(g, &As[(wv * 32 + ch * 16) * 32]);
            }
        }
        if constexpr (WMODE == 0) {
            const float* W = (const float*)Wp;
            #pragma unroll
            for (int it = 0; it < 2; it++) {
                int row = it * 64 + (tid >> 2);
                int col = (tid & 3) * 8;
                const float4* p = (const float4*)(W + (size_t)(n0 + row) * K + k0 + col);
                float4 u0 = p[0], u1 = p[1];
                bf16x8 v;
                v[0] = (bf16)u0.x; v[1] = (bf16)u0.y; v[2] = (bf16)u0.z; v[3] = (bf16)u0.w;
                v[4] = (bf16)u1.x; v[5] = (bf16)u1.y; v[6] = (bf16)u1.z; v[7] = (bf16)u1.w;
                *(bf16x8*)(&Ws[row * 32 + col]) = v;
            }
        } else {
            const bf16* W = (const bf16*)Wp;
            #pragma unroll
            for (int ch = 0; ch < 2; ch++) {
                int row = wv * 32 + ch * 16 + arow;
                const bf16* g = W + (size_t)(n0 + row) * K + k0 + acol;
                async16(g, &Ws[(wv * 32 + ch * 16) * 32]);
            }
        }
        __syncthreads();

        bf16x8 af[4], bw[4];
        #pragma unroll
        for (int i = 0; i < 4; i++) af[i] = *(const bf16x8*)(&As[(wm + i * 16 + c) * 32 + quad * 8]);
        #pragma unroll
        for (int j = 0; j < 4; j++) bw[j] = *(const bf16x8*)(&Ws[(wn + j * 16 + c) * 32 + quad * 8]);
        #pragma unroll
        for (int i = 0; i < 4; i++)
            #pragma unroll
            for (int j = 0; j < 4; j++)
                acc[i][j] = __builtin_amdgcn_mfma_f32_16x16x32_bf16(af[i], bw[j], acc[i][j], 0, 0, 0);
        __syncthreads();
    }

    // ---- epilogue.  C/D layout: col = lane&15, row = quad*4+reg ----
    if constexpr (CMODE == 0) {
        float* C = (float*)Cp;
        #pragma unroll
        for (int i = 0; i < 4; i++)
            #pragma unroll
            for (int j = 0; j < 4; j++)
                #pragma unroll
                for (int r = 0; r < 4; r++) {
                    int m = m0 + wm + i * 16 + quad * 4 + r;
                    int n = n0 + wn + j * 16 + c;
                    C[(size_t)m * N + n] = acc[i][j][r];
                }
    } else if constexpr (CMODE == 1) {
        bf16* C = (bf16*)Cp;
        const int b = m0 >> 11;
        #pragma unroll
        for (int j = 0; j < 4; j++) {
            int n = n0 + wn + j * 16 + c;
            size_t base = ((size_t)(b * (N >> 7) + (n >> 7)) * 2048) * 128 + (n & 127);
            #pragma unroll
            for (int i = 0; i < 4; i++)
                #pragma unroll
                for (int r = 0; r < 4; r++) {
                    int s = (m0 & 2047) + wm + i * 16 + quad * 4 + r;
                    C[base + (size_t)s * 128] = (bf16)acc[i][j][r];
                }
        }
    } else if constexpr (CMODE == 2) {   // V^T  [B][N][2048]
        bf16* C = (bf16*)Cp;
        const int b = m0 >> 11;
        #pragma unroll
        for (int j = 0; j < 4; j++) {
            int n = n0 + wn + j * 16 + c;
            size_t base = ((size_t)b * N + n) * 2048;
            #pragma unroll
            for (int i = 0; i < 4; i++) {
                int s0 = (m0 & 2047) + wm + i * 16 + quad * 4;
                bf16x4 v;
                #pragma unroll
                for (int r = 0; r < 4; r++) v[r] = (bf16)acc[i][j][r];
                *(bf16x4*)(&C[base + s0]) = v;
            }
        }
    } else {   // CMODE 3: fused QKV
        bf16* Cq = (bf16*)Cp;
        const int b = m0 >> 11;
        if (n0 < 2048) {
            #pragma unroll
            for (int j = 0; j < 4; j++) {
                int n = n0 + wn + j * 16 + c;
                size_t base = ((size_t)(b * 16 + (n >> 7)) * 2048) * 128 + (n & 127);
                #pragma unroll
                for (int i = 0; i < 4; i++)
                    #pragma unroll
                    for (int r = 0; r < 4; r++) {
                        int s = (m0 & 2047) + wm + i * 16 + quad * 4 + r;
                        Cq[base + (size_t)s * 128] = (bf16)acc[i][j][r];
                    }
            }
        } else if (n0 < 3072) {
            bf16* Ck = Cq + XN;
            #pragma unroll
            for (int j = 0; j < 4; j++) {
                int n = n0 - 2048 + wn + j * 16 + c;
                size_t base = ((size_t)(b * 8 + (n >> 7)) * 2048) * 128 + (n & 127);
                #pragma unroll
                for (int i = 0; i < 4; i++)
                    #pragma unroll
                    for (int r = 0; r < 4; r++) {
                        int s = (m0 & 2047) + wm + i * 16 + quad * 4 + r;
                        Ck[base + (size_t)s * 128] = (bf16)acc[i][j][r];
                    }
            }
        } else {
            bf16* Cv = Cq + XN + QWN;
            #pragma unroll
            for (int j = 0; j < 4; j++) {
                int n = n0 - 3072 + wn + j * 16 + c;
                size_t base = ((size_t)b * 1024 + n) * 2048;
                #pragma unroll
                for (int i = 0; i < 4; i++) {
                    int s0 = (m0 & 2047) + wm + i * 16 + quad * 4;
                    bf16x4 v;
                    #pragma unroll
                    for (int r = 0; r < 4; r++) v[r] = (bf16)acc[i][j][r];
                    *(bf16x4*)(&Cv[base + s0]) = v;
                }
            }
        }
    }
}

// ---------------------------------------------------------------------------
// RMSNorm(D=128) + RoPE, in place on head-major bf16 q/k.
// ---------------------------------------------------------------------------
__global__ __launch_bounds__(128) void norm_rope(bf16* __restrict__ q,
                                                 bf16* __restrict__ k,
                                                 const float* __restrict__ pe,
                                                 const float* __restrict__ qnw,
                                                 const float* __restrict__ knw)
{
    const int s  = blockIdx.x;
    const int hh = blockIdx.y;
    const int b  = blockIdx.z;
    const int d  = threadIdx.x;

    bf16* buf;
    const float* w;
    if (hh < NH) {
        buf = q + ((size_t)(b * NH + hh) * SEQ + s) * HD;
        w = qnw;
    } else {
        buf = k + ((size_t)(b * NKV + (hh - NH)) * SEQ + s) * HD;
        w = knw;
    }

    float x = (float)buf[d];
    float ss = x * x;
    #pragma unroll
    for (int m = 32; m; m >>= 1) ss += __shfl_xor(ss, m);

    __shared__ float red[2];
    __shared__ float nv[128];
    if ((d & 63) == 0) red[d >> 6] = ss;
    __syncthreads();
    float var = (red[0] + red[1]) * (1.0f / 128.0f);
    float nx = x * rsqrtf(var + 1e-6f) * w[d];
    nv[d] = nx;
    __syncthreads();

    const float* pev = pe + ((size_t)b * SEQ + s) * HD;
    float o;
    if (d < 64) {
        o = nx * pev[d] - nv[d + 64] * pev[64 + d];
    } else {
        o = nv[d - 64] * pev[d] + nx * pev[d - 64];
    }
    buf[d] = (bf16)o;
}

// ---------------------------------------------------------------------------
// Flash attention, causal, GQA rep=2.  64q rows per block (wave owns 16),
// 64-key tiles.  Static-max softmax (RMS=1 rows + norm-preserving RoPE =>
// |score*scale| <= sqrt(D)*(1+eps) ~ 11.36; bound M=11.5): no in-loop
// reductions; partials combine by addition; l reduced once in epilogue.
// Cross-barrier register prefetch: tile kt+1's K/V global loads issue right
// after the barrier and are consumed at the next iteration's ds_write, so
// the compute phase covers the global-load latency.
// ---------------------------------------------------------------------------
__global__ __launch_bounds__(256) void fattn(bf16* __restrict__ O,
                                             const bf16* __restrict__ Q,
                                             const bf16* __restrict__ Kh,
                                             const bf16* __restrict__ Vtg)
{
    const int qblk = (int)gridDim.x - 1 - (int)blockIdx.x;   // heavy first
    const int h    = blockIdx.y;
    const int b    = blockIdx.z;
    const int kv   = h >> 1;

    const int tid  = threadIdx.x;
    const int wv   = tid >> 6;
    const int lane = tid & 63;
    const int quad = lane >> 4;
    const int c    = lane & 15;

    __shared__ bf16 Ks[64 * 136];        // [key][d]
    __shared__ bf16 Vs[128 * 72];        // [d][key]
    __shared__ bf16 Ps[4 * 16 * 72];     // per-wave P tile

    const int qw = qblk * 64 + wv * 16;

    bf16x8 qf[4];
    {
        const bf16* qp = Q + ((size_t)(b * NH + h) * SEQ + qw + c) * HD + quad * 8;
        #pragma unroll
        for (int t = 0; t < 4; t++) qf[t] = *(const bf16x8*)(qp + t * 32);
    }

    floatx4 o_acc[8] = {};
    float l_part[4] = {};

    const bf16* kbase = Kh  + (size_t)(b * NKV + kv) * SEQ * HD;
    const bf16* vbase = Vtg + (size_t)(b * NKV + kv) * HD * SEQ;

    const int kr  = tid >> 2, ksc = (tid & 3) * 32;   // K staging: 64 rows x 128
    const int vd  = tid >> 1, vkc = (tid & 1) * 32;   // V^T staging: 128 rows x 64
    bf16* psw = &Ps[wv * 16 * 72];
    const int nkt = qblk + 1;
    const float kS = 0.08838834764831845f * 1.4426950408889634f;  // scale*log2e
    const float kB = 11.5f * 1.4426950408889634f;                 // M*log2e

    // ---- prologue: load tile 0 into registers ----
    bf16x8 kreg[4], vreg[4];
    {
        const bf16* kp = kbase + (size_t)kr * HD + ksc;
        const bf16* vp = vbase + (size_t)vd * SEQ + vkc;
        #pragma unroll
        for (int i = 0; i < 4; i++) kreg[i] = *(const bf16x8*)(kp + i * 8);
        #pragma unroll
        for (int i = 0; i < 4; i++) vreg[i] = *(const bf16x8*)(vp + i * 8);
    }

    for (int kt = 0; kt < nkt; kt++) {
        const int k0 = kt * 64;
        // ---- commit prefetched tile to LDS ----
        #pragma unroll
        for (int i = 0; i < 4; i++)
            *(bf16x8*)(&Ks[kr * 136 + ksc + i * 8]) = kreg[i];
        #pragma unroll
        for (int i = 0; i < 4; i++)
            *(bf16x8*)(&Vs[vd * 72 + vkc + i * 8]) = vreg[i];
        __syncthreads();

        // ---- prefetch next tile (latency covered by compute below) ----
        if (kt + 1 < nkt) {
            const bf16* kp = kbase + (size_t)(k0 + 64 + kr) * HD + ksc;
            const bf16* vp = vbase + (size_t)vd * SEQ + (k0 + 64) + vkc;
            #pragma unroll
            for (int i = 0; i < 4; i++) kreg[i] = *(const bf16x8*)(kp + i * 8);
            #pragma unroll
            for (int i = 0; i < 4; i++) vreg[i] = *(const bf16x8*)(vp + i * 8);
        }

        // ---- QK^T: 16 q-rows x 64 keys ----
        floatx4 sc[4] = {};
        #pragma unroll
        for (int t = 0; t < 4; t++) {
            #pragma unroll
            for (int g = 0; g < 4; g++) {
                bf16x8 kf = *(const bf16x8*)(&Ks[(g * 16 + c) * 136 + t * 32 + quad * 8]);
                sc[g] = __builtin_amdgcn_mfma_f32_16x16x32_bf16(qf[t], kf, sc[g], 0, 0, 0);
            }
        }

        // ---- static-max softmax + P store (no reductions) ----
        const bool last = (kt == nkt - 1);
        #pragma unroll
        for (int r = 0; r < 4; r++) {
            const int qrow = qw + quad * 4 + r;
            #pragma unroll
            for (int g = 0; g < 4; g++) {
                float p = exp2f(sc[g][r] * kS - kB);
                if (last && (k0 + g * 16 + c > qrow)) p = 0.0f;
                l_part[r] += p;
                psw[(quad * 4 + r) * 72 + g * 16 + c] = (bf16)p;
            }
        }
        // drain ds_writes before wave-local ds_reads (vmcnt untouched)
        asm volatile("s_waitcnt lgkmcnt(0)" ::: "memory");
        bf16x8 pf0 = *(const bf16x8*)(&psw[c * 72 + quad * 8]);
        bf16x8 pf1 = *(const bf16x8*)(&psw[c * 72 + 32 + quad * 8]);

        // ---- PV ----
        #pragma unroll
        for (int f = 0; f < 8; f++) {
            bf16x8 vf0 = *(const bf16x8*)(&Vs[(f * 16 + c) * 72 + quad * 8]);
            bf16x8 vf1 = *(const bf16x8*)(&Vs[(f * 16 + c) * 72 + 32 + quad * 8]);
            o_acc[f] = __builtin_amdgcn_mfma_f32_16x16x32_bf16(pf0, vf0, o_acc[f], 0, 0, 0);
            o_acc[f] = __builtin_amdgcn_mfma_f32_16x16x32_bf16(pf1, vf1, o_acc[f], 0, 0, 0);
        }
        __syncthreads();
    }

    // ---- epilogue: one l-reduction per row, normalize, store ----
    #pragma unroll
    for (int r = 0; r < 4; r++) {
        float l = l_part[r];
        #pragma unroll
        for (int msk = 8; msk; msk >>= 1) l += __shfl_xor(l, msk);
        const float inv = 1.0f / l;
        bf16* op = O + ((size_t)(b * NH + h) * SEQ + qw + quad * 4 + r) * HD;
        #pragma unroll
        for (int f = 0; f < 8; f++) op[f * 16 + c] = (bf16)(o_acc[f][r] * inv);
    }
}

// ---------------------------------------------------------------------------
extern "C" void kernel_launch(void* const* d_in, const int* in_sizes, int n_in,
                              void* d_out, int out_size, void* d_ws, size_t ws_size,
                              hipStream_t stream)
{
    const float* x   = (const float*)d_in[0];
    const float* pe  = (const float*)d_in[1];
    const float* qw  = (const float*)d_in[2];
    const float* kw  = (const float*)d_in[3];
    const float* vw  = (const float*)d_in[4];
    const float* ow  = (const float*)d_in[5];
    const float* qnw = (const float*)d_in[6];
    const float* knw = (const float*)d_in[7];
    float* out = (float*)d_out;

    bf16* qb = (bf16*)d_ws;          // [B][NH][S][HD]   head-major
    bf16* kb = qb + XN;              // [B][NKV][S][HD]  head-major
    bf16* vt = kb + KWN * 2;         // [B][NKV][HD][S]  V^T
    bf16* ab = vt + VWN * 2;         // [B][NH][S][HD]   head-major
    bf16* cvt_base = ab + XN;

    const bool fit = ws_size >= (size_t)92274688;
    const int M = BATCH * SEQ;

    if (fit) {
        bf16* xb  = cvt_base;
        bf16* qwb = xb  + XN;     // qwb|kwb|vwb contiguous => fused QKV weight [4096][2048]
        bf16* kwb = qwb + QWN;
        bf16* vwb = kwb + KWN;
        bf16* owb = vwb + VWN;
        cvt<<<XN  / 8 / 256, 256, 0, stream>>>(xb,  x,  (int)XN);
        cvt<<<QWN / 8 / 256, 256, 0, stream>>>(qwb, qw, (int)QWN);
        cvt<<<KWN / 8 / 256, 256, 0, stream>>>(kwb, kw, (int)KWN);
        cvt<<<VWN / 8 / 256, 256, 0, stream>>>(vwb, vw, (int)VWN);
        cvt<<<OWN / 8 / 256, 256, 0, stream>>>(owb, ow, (int)OWN);

        // fused Q|K|V projection: N = 2048+1024+1024, 1024 blocks
        gemm128<1, 1, 3><<<dim3(32, 32), 256, 0, stream>>>(qb, xb, qwb, M, 4096, 2048);

        norm_rope<<<dim3(SEQ, NH + NKV, BATCH), 128, 0, stream>>>(qb, kb, pe, qnw, knw);
        fattn<<<dim3(SEQ / 64, NH, BATCH), 256, 0, stream>>>(ab, qb, kb, vt);

        gemm128<2, 1, 0><<<dim3(32, 16), 256, 0, stream>>>(out, ab, owb, M, 2048, 2048);
    } else {
        gemm128<0, 0, 1><<<dim3(32, 16), 256, 0, stream>>>(qb, x, qw, M, 2048, 2048);
        gemm128<0, 0, 1><<<dim3(32,  8), 256, 0, stream>>>(kb, x, kw, M, 1024, 2048);
        gemm128<0, 0, 2><<<dim3(32,  8), 256, 0, stream>>>(vt, x, vw, M, 1024, 2048);

        norm_rope<<<dim3(SEQ, NH + NKV, BATCH), 128, 0, stream>>>(qb, kb, pe, qnw, knw);
        fattn<<<dim3(SEQ / 64, NH, BATCH), 256, 0, stream>>>(ab, qb, kb, vt);

        gemm128<2, 0, 0><<<dim3(32, 16), 256, 0, stream>>>(out, ab, ow, M, 2048, 2048);
    }
}

// Round 6
// 427.491 us; speedup vs baseline: 1.3883x; 1.0931x over previous
//
#include <hip/hip_runtime.h>
#include <hip/hip_bf16.h>

#define BATCH 2
#define SEQ   2048
#define HID   2048
#define NH    16
#define NKV   8
#define HD    128

typedef __bf16 bf16;
typedef bf16  bf16x8  __attribute__((ext_vector_type(8)));
typedef bf16  bf16x4  __attribute__((ext_vector_type(4)));
typedef float floatx4 __attribute__((ext_vector_type(4)));

typedef __attribute__((address_space(3))) void lds_void;
typedef const __attribute__((address_space(1))) void gmem_void;

__device__ inline void async16(const void* g, void* l) {
    __builtin_amdgcn_global_load_lds((gmem_void*)g, (lds_void*)l, 16, 0, 0);
}

// workspace layout constants (elements)
#define XN  8388608u
#define QWN 4194304u
#define KWN 2097152u
#define VWN 2097152u
#define OWN 4194304u

// ---------------------------------------------------------------------------
// f32 -> bf16 bulk convert (memory-bound)
// ---------------------------------------------------------------------------
__global__ __launch_bounds__(256) void cvt(bf16* __restrict__ dst,
                                           const float* __restrict__ src, int n)
{
    int i = (blockIdx.x * 256 + threadIdx.x) * 8;
    if (i >= n) return;
    const float4* p = (const float4*)(src + i);
    float4 u0 = p[0], u1 = p[1];
    bf16x8 v;
    v[0] = (bf16)u0.x; v[1] = (bf16)u0.y; v[2] = (bf16)u0.z; v[3] = (bf16)u0.w;
    v[4] = (bf16)u1.x; v[5] = (bf16)u1.y; v[6] = (bf16)u1.z; v[7] = (bf16)u1.w;
    *(bf16x8*)(dst + i) = v;
}

// ---------------------------------------------------------------------------
// GEMM  C = A[M,K] * W[N,K]^T, 128x128 tile, BK=32, m97 structure.
// AMODE: 0 = A f32 row-major (manual cvt stage)
//        1 = A bf16 row-major (global_load_lds)
// WMODE: 0 = W f32 (manual cvt)   1 = W bf16 (global_load_lds)
// CMODE: 0 = C f32 row-major      1 = C bf16 row-major
//        2 = C bf16 transposed [B][N][2048] (V^T)
//        3 = fused QKV epilogue: q row-major [B][S][2048] at Cp; k row-major
//            [B][S][1024] at Cp+XN; v^T [B][1024][2048] at Cp+XN+QWN.
// ---------------------------------------------------------------------------
template <int AMODE, int WMODE, int CMODE>
__global__ __launch_bounds__(256) void gemm128(void* __restrict__ Cp,
                                               const void* __restrict__ Ap,
                                               const void* __restrict__ Wp,
                                               int M, int N, int K)
{
    __shared__ bf16 As[128 * 32];
    __shared__ bf16 Ws[128 * 32];

    const int tid  = threadIdx.x;
    const int wv   = tid >> 6;
    const int lane = tid & 63;
    const int quad = lane >> 4;
    const int c    = lane & 15;

    const int m0 = blockIdx.x * 128;
    const int n0 = blockIdx.y * 128;
    const int wm = (wv >> 1) * 64;
    const int wn = (wv & 1) * 64;

    const int arow = lane >> 2;
    const int acol = (lane & 3) * 8;

    floatx4 acc[4][4] = {};

    for (int k0 = 0; k0 < K; k0 += 32) {
        if constexpr (AMODE == 0) {
            const float* A = (const float*)Ap;
            #pragma unroll
            for (int it = 0; it < 2; it++) {
                int row = it * 64 + (tid >> 2);
                int col = (tid & 3) * 8;
                const float4* p = (const float4*)(A + (size_t)(m0 + row) * K + k0 + col);
                float4 u0 = p[0], u1 = p[1];
                bf16x8 v;
                v[0] = (bf16)u0.x; v[1] = (bf16)u0.y; v[2] = (bf16)u0.z; v[3] = (bf16)u0.w;
                v[4] = (bf16)u1.x; v[5] = (bf16)u1.y; v[6] = (bf16)u1.z; v[7] = (bf16)u1.w;
                *(bf16x8*)(&As[row * 32 + col]) = v;
            }
        } else {
            const bf16* A = (const bf16*)Ap;
            #pragma unroll
            for (int ch = 0; ch < 2; ch++) {
                int row = wv * 32 + ch * 16 + arow;
                const bf16* g = A + (size_t)(m0 + row) * K + k0 + acol;
                async16(g, &As[(wv * 32 + ch * 16) * 32]);
            }
        }
        if constexpr (WMODE == 0) {
            const float* W = (const float*)Wp;
            #pragma unroll
            for (int it = 0; it < 2; it++) {
                int row = it * 64 + (tid >> 2);
                int col = (tid & 3) * 8;
                const float4* p = (const float4*)(W + (size_t)(n0 + row) * K + k0 + col);
                float4 u0 = p[0], u1 = p[1];
                bf16x8 v;
                v[0] = (bf16)u0.x; v[1] = (bf16)u0.y; v[2] = (bf16)u0.z; v[3] = (bf16)u0.w;
                v[4] = (bf16)u1.x; v[5] = (bf16)u1.y; v[6] = (bf16)u1.z; v[7] = (bf16)u1.w;
                *(bf16x8*)(&Ws[row * 32 + col]) = v;
            }
        } else {
            const bf16* W = (const bf16*)Wp;
            #pragma unroll
            for (int ch = 0; ch < 2; ch++) {
                int row = wv * 32 + ch * 16 + arow;
                const bf16* g = W + (size_t)(n0 + row) * K + k0 + acol;
                async16(g, &Ws[(wv * 32 + ch * 16) * 32]);
            }
        }
        __syncthreads();

        bf16x8 af[4], bw[4];
        #pragma unroll
        for (int i = 0; i < 4; i++) af[i] = *(const bf16x8*)(&As[(wm + i * 16 + c) * 32 + quad * 8]);
        #pragma unroll
        for (int j = 0; j < 4; j++) bw[j] = *(const bf16x8*)(&Ws[(wn + j * 16 + c) * 32 + quad * 8]);
        #pragma unroll
        for (int i = 0; i < 4; i++)
            #pragma unroll
            for (int j = 0; j < 4; j++)
                acc[i][j] = __builtin_amdgcn_mfma_f32_16x16x32_bf16(af[i], bw[j], acc[i][j], 0, 0, 0);
        __syncthreads();
    }

    // ---- epilogue.  C/D layout: col = lane&15, row = quad*4+reg ----
    if constexpr (CMODE == 0) {
        float* C = (float*)Cp;
        #pragma unroll
        for (int i = 0; i < 4; i++)
            #pragma unroll
            for (int j = 0; j < 4; j++)
                #pragma unroll
                for (int r = 0; r < 4; r++) {
                    int m = m0 + wm + i * 16 + quad * 4 + r;
                    int n = n0 + wn + j * 16 + c;
                    C[(size_t)m * N + n] = acc[i][j][r];
                }
    } else if constexpr (CMODE == 1) {
        bf16* C = (bf16*)Cp;
        #pragma unroll
        for (int i = 0; i < 4; i++)
            #pragma unroll
            for (int j = 0; j < 4; j++)
                #pragma unroll
                for (int r = 0; r < 4; r++) {
                    int m = m0 + wm + i * 16 + quad * 4 + r;
                    int n = n0 + wn + j * 16 + c;
                    C[(size_t)m * N + n] = (bf16)acc[i][j][r];
                }
    } else if constexpr (CMODE == 2) {   // V^T  [B][N][2048]
        bf16* C = (bf16*)Cp;
        const int b = m0 >> 11;
        #pragma unroll
        for (int j = 0; j < 4; j++) {
            int n = n0 + wn + j * 16 + c;
            size_t base = ((size_t)b * N + n) * 2048;
            #pragma unroll
            for (int i = 0; i < 4; i++) {
                int s0 = (m0 & 2047) + wm + i * 16 + quad * 4;
                bf16x4 v;
                #pragma unroll
                for (int r = 0; r < 4; r++) v[r] = (bf16)acc[i][j][r];
                *(bf16x4*)(&C[base + s0]) = v;
            }
        }
    } else {   // CMODE 3: fused QKV (row-major q,k; transposed v)
        bf16* Cq = (bf16*)Cp;
        if (n0 < 2048) {
            #pragma unroll
            for (int i = 0; i < 4; i++)
                #pragma unroll
                for (int j = 0; j < 4; j++)
                    #pragma unroll
                    for (int r = 0; r < 4; r++) {
                        int m = m0 + wm + i * 16 + quad * 4 + r;
                        int n = n0 + wn + j * 16 + c;
                        Cq[(size_t)m * 2048 + n] = (bf16)acc[i][j][r];
                    }
        } else if (n0 < 3072) {
            bf16* Ck = Cq + XN;
            #pragma unroll
            for (int i = 0; i < 4; i++)
                #pragma unroll
                for (int j = 0; j < 4; j++)
                    #pragma unroll
                    for (int r = 0; r < 4; r++) {
                        int m = m0 + wm + i * 16 + quad * 4 + r;
                        int n = n0 - 2048 + wn + j * 16 + c;
                        Ck[(size_t)m * 1024 + n] = (bf16)acc[i][j][r];
                    }
        } else {
            bf16* Cv = Cq + XN + QWN;
            const int b = m0 >> 11;
            #pragma unroll
            for (int j = 0; j < 4; j++) {
                int n = n0 - 3072 + wn + j * 16 + c;
                size_t base = ((size_t)b * 1024 + n) * 2048;
                #pragma unroll
                for (int i = 0; i < 4; i++) {
                    int s0 = (m0 & 2047) + wm + i * 16 + quad * 4;
                    bf16x4 v;
                    #pragma unroll
                    for (int r = 0; r < 4; r++) v[r] = (bf16)acc[i][j][r];
                    *(bf16x4*)(&Cv[base + s0]) = v;
                }
            }
        }
    }
}

// ---------------------------------------------------------------------------
// RMSNorm(D=128) + RoPE, in place on row-major bf16 q [B][S][2048] /
// k [B][S][1024].  grid = (SEQ, NH+NKV, BATCH), block = 128
// ---------------------------------------------------------------------------
__global__ __launch_bounds__(128) void norm_rope(bf16* __restrict__ q,
                                                 bf16* __restrict__ k,
                                                 const float* __restrict__ pe,
                                                 const float* __restrict__ qnw,
                                                 const float* __restrict__ knw)
{
    const int s  = blockIdx.x;
    const int hh = blockIdx.y;
    const int b  = blockIdx.z;
    const int d  = threadIdx.x;

    bf16* buf;
    const float* w;
    if (hh < NH) {
        buf = q + (size_t)(b * SEQ + s) * 2048 + hh * HD;
        w = qnw;
    } else {
        buf = k + (size_t)(b * SEQ + s) * 1024 + (hh - NH) * HD;
        w = knw;
    }

    float x = (float)buf[d];
    float ss = x * x;
    #pragma unroll
    for (int m = 32; m; m >>= 1) ss += __shfl_xor(ss, m);

    __shared__ float red[2];
    __shared__ float nv[128];
    if ((d & 63) == 0) red[d >> 6] = ss;
    __syncthreads();
    float var = (red[0] + red[1]) * (1.0f / 128.0f);
    float nx = x * rsqrtf(var + 1e-6f) * w[d];
    nv[d] = nx;
    __syncthreads();

    const float* pev = pe + ((size_t)b * SEQ + s) * HD;
    float o;
    if (d < 64) {
        o = nx * pev[d] - nv[d + 64] * pev[64 + d];
    } else {
        o = nv[d - 64] * pev[d] + nx * pev[d - 64];
    }
    buf[d] = (bf16)o;
}

// ---------------------------------------------------------------------------
// Flash attention, causal, GQA rep=2.  64q rows per block (wave owns 16),
// 64-key tiles, static-max softmax, register prefetch across the barrier.
// Row-major Q [B][S][2048], K [B][S][1024]; V^T [B][1024][2048].
// Per-CU load balance: breadth-first dispatch puts blocks {i, i+256, ...}
// on one CU; those share x and differ in y by 8.  qblk = (h&8) ? x : 31-x
// pairs qblk q with 31-q on every CU => constant 66 tiles/CU.
// ---------------------------------------------------------------------------
__global__ __launch_bounds__(256) void fattn(bf16* __restrict__ O,
                                             const bf16* __restrict__ Q,
                                             const bf16* __restrict__ Kh,
                                             const bf16* __restrict__ Vtg)
{
    const int h    = blockIdx.y;
    const int b    = blockIdx.z;
    const int qblk = (h & 8) ? (int)blockIdx.x
                             : ((int)gridDim.x - 1 - (int)blockIdx.x);
    const int kv   = h >> 1;

    const int tid  = threadIdx.x;
    const int wv   = tid >> 6;
    const int lane = tid & 63;
    const int quad = lane >> 4;
    const int c    = lane & 15;

    __shared__ bf16 Ks[64 * 136];        // [key][d]
    __shared__ bf16 Vs[128 * 72];        // [d][key]
    __shared__ bf16 Ps[4 * 16 * 72];     // per-wave P tile

    const int qw = qblk * 64 + wv * 16;

    bf16x8 qf[4];
    {
        const bf16* qp = Q + (size_t)(b * SEQ + qw + c) * 2048 + h * HD + quad * 8;
        #pragma unroll
        for (int t = 0; t < 4; t++) qf[t] = *(const bf16x8*)(qp + t * 32);
    }

    floatx4 o_acc[8] = {};
    float l_part[4] = {};

    const bf16* kbase = Kh  + (size_t)b * SEQ * 1024 + kv * HD;        // + s*1024
    const bf16* vbase = Vtg + ((size_t)b * 1024 + kv * HD) * 2048;     // + d*2048

    const int kr  = tid >> 2, ksc = (tid & 3) * 32;   // K staging: 64 rows x 128
    const int vd  = tid >> 1, vkc = (tid & 1) * 32;   // V^T staging: 128 rows x 64
    bf16* psw = &Ps[wv * 16 * 72];
    const int nkt = qblk + 1;
    const float kS = 0.08838834764831845f * 1.4426950408889634f;  // scale*log2e
    const float kB = 11.5f * 1.4426950408889634f;                 // M*log2e

    // ---- prologue: load tile 0 into registers ----
    bf16x8 kreg[4], vreg[4];
    {
        const bf16* kp = kbase + (size_t)kr * 1024 + ksc;
        const bf16* vp = vbase + (size_t)vd * 2048 + vkc;
        #pragma unroll
        for (int i = 0; i < 4; i++) kreg[i] = *(const bf16x8*)(kp + i * 8);
        #pragma unroll
        for (int i = 0; i < 4; i++) vreg[i] = *(const bf16x8*)(vp + i * 8);
    }

    for (int kt = 0; kt < nkt; kt++) {
        const int k0 = kt * 64;
        // ---- commit prefetched tile to LDS ----
        #pragma unroll
        for (int i = 0; i < 4; i++)
            *(bf16x8*)(&Ks[kr * 136 + ksc + i * 8]) = kreg[i];
        #pragma unroll
        for (int i = 0; i < 4; i++)
            *(bf16x8*)(&Vs[vd * 72 + vkc + i * 8]) = vreg[i];
        __syncthreads();

        // ---- prefetch next tile (latency covered by compute below) ----
        if (kt + 1 < nkt) {
            const bf16* kp = kbase + (size_t)(k0 + 64 + kr) * 1024 + ksc;
            const bf16* vp = vbase + (size_t)vd * 2048 + (k0 + 64) + vkc;
            #pragma unroll
            for (int i = 0; i < 4; i++) kreg[i] = *(const bf16x8*)(kp + i * 8);
            #pragma unroll
            for (int i = 0; i < 4; i++) vreg[i] = *(const bf16x8*)(vp + i * 8);
        }

        // ---- QK^T: 16 q-rows x 64 keys ----
        floatx4 sc[4] = {};
        #pragma unroll
        for (int t = 0; t < 4; t++) {
            #pragma unroll
            for (int g = 0; g < 4; g++) {
                bf16x8 kf = *(const bf16x8*)(&Ks[(g * 16 + c) * 136 + t * 32 + quad * 8]);
                sc[g] = __builtin_amdgcn_mfma_f32_16x16x32_bf16(qf[t], kf, sc[g], 0, 0, 0);
            }
        }

        // ---- static-max softmax + P store (no reductions) ----
        const bool last = (kt == nkt - 1);
        #pragma unroll
        for (int r = 0; r < 4; r++) {
            const int qrow = qw + quad * 4 + r;
            #pragma unroll
            for (int g = 0; g < 4; g++) {
                float p = exp2f(sc[g][r] * kS - kB);
                if (last && (k0 + g * 16 + c > qrow)) p = 0.0f;
                l_part[r] += p;
                psw[(quad * 4 + r) * 72 + g * 16 + c] = (bf16)p;
            }
        }
        // drain ds_writes before wave-local ds_reads (vmcnt untouched)
        asm volatile("s_waitcnt lgkmcnt(0)" ::: "memory");
        bf16x8 pf0 = *(const bf16x8*)(&psw[c * 72 + quad * 8]);
        bf16x8 pf1 = *(const bf16x8*)(&psw[c * 72 + 32 + quad * 8]);

        // ---- PV ----
        #pragma unroll
        for (int f = 0; f < 8; f++) {
            bf16x8 vf0 = *(const bf16x8*)(&Vs[(f * 16 + c) * 72 + quad * 8]);
            bf16x8 vf1 = *(const bf16x8*)(&Vs[(f * 16 + c) * 72 + 32 + quad * 8]);
            o_acc[f] = __builtin_amdgcn_mfma_f32_16x16x32_bf16(pf0, vf0, o_acc[f], 0, 0, 0);
            o_acc[f] = __builtin_amdgcn_mfma_f32_16x16x32_bf16(pf1, vf1, o_acc[f], 0, 0, 0);
        }
        __syncthreads();
    }

    // ---- epilogue: one l-reduction per row, normalize, store ----
    #pragma unroll
    for (int r = 0; r < 4; r++) {
        float l = l_part[r];
        #pragma unroll
        for (int msk = 8; msk; msk >>= 1) l += __shfl_xor(l, msk);
        const float inv = 1.0f / l;
        bf16* op = O + (size_t)(b * SEQ + qw + quad * 4 + r) * 2048 + h * HD;
        #pragma unroll
        for (int f = 0; f < 8; f++) op[f * 16 + c] = (bf16)(o_acc[f][r] * inv);
    }
}

// ---------------------------------------------------------------------------
extern "C" void kernel_launch(void* const* d_in, const int* in_sizes, int n_in,
                              void* d_out, int out_size, void* d_ws, size_t ws_size,
                              hipStream_t stream)
{
    const float* x   = (const float*)d_in[0];
    const float* pe  = (const float*)d_in[1];
    const float* qw  = (const float*)d_in[2];
    const float* kw  = (const float*)d_in[3];
    const float* vw  = (const float*)d_in[4];
    const float* ow  = (const float*)d_in[5];
    const float* qnw = (const float*)d_in[6];
    const float* knw = (const float*)d_in[7];
    float* out = (float*)d_out;

    bf16* qb = (bf16*)d_ws;          // [B][S][2048]   row-major
    bf16* kb = qb + XN;              // [B][S][1024]   row-major
    bf16* vt = kb + KWN * 2;         // [B][1024][2048] V^T
    bf16* ab = vt + VWN * 2;         // [B][S][2048]   row-major
    bf16* cvt_base = ab + XN;

    const bool fit = ws_size >= (size_t)92274688;
    const int M = BATCH * SEQ;

    if (fit) {
        bf16* xb  = cvt_base;
        bf16* qwb = xb  + XN;     // qwb|kwb|vwb contiguous => fused QKV weight [4096][2048]
        bf16* kwb = qwb + QWN;
        bf16* vwb = kwb + KWN;
        bf16* owb = vwb + VWN;
        cvt<<<XN  / 8 / 256, 256, 0, stream>>>(xb,  x,  (int)XN);
        cvt<<<QWN / 8 / 256, 256, 0, stream>>>(qwb, qw, (int)QWN);
        cvt<<<KWN / 8 / 256, 256, 0, stream>>>(kwb, kw, (int)KWN);
        cvt<<<VWN / 8 / 256, 256, 0, stream>>>(vwb, vw, (int)VWN);
        cvt<<<OWN / 8 / 256, 256, 0, stream>>>(owb, ow, (int)OWN);

        // fused Q|K|V projection: N = 2048+1024+1024, 1024 blocks
        gemm128<1, 1, 3><<<dim3(32, 32), 256, 0, stream>>>(qb, xb, qwb, M, 4096, 2048);

        norm_rope<<<dim3(SEQ, NH + NKV, BATCH), 128, 0, stream>>>(qb, kb, pe, qnw, knw);
        fattn<<<dim3(SEQ / 64, NH, BATCH), 256, 0, stream>>>(ab, qb, kb, vt);

        gemm128<1, 1, 0><<<dim3(32, 16), 256, 0, stream>>>(out, ab, owb, M, 2048, 2048);
    } else {
        gemm128<0, 0, 1><<<dim3(32, 16), 256, 0, stream>>>(qb, x, qw, M, 2048, 2048);
        gemm128<0, 0, 1><<<dim3(32,  8), 256, 0, stream>>>(kb, x, kw, M, 1024, 2048);
        gemm128<0, 0, 2><<<dim3(32,  8), 256, 0, stream>>>(vt, x, vw, M, 1024, 2048);

        norm_rope<<<dim3(SEQ, NH + NKV, BATCH), 128, 0, stream>>>(qb, kb, pe, qnw, knw);
        fattn<<<dim3(SEQ / 64, NH, BATCH), 256, 0, stream>>>(ab, qb, kb, vt);

        gemm128<0, 0, 0><<<dim3(32, 16), 256, 0, stream>>>(out, ab, ow, M, 2048, 2048);
    }
}

// Round 7
// 421.473 us; speedup vs baseline: 1.4081x; 1.0143x over previous
//
#include <hip/hip_runtime.h>
#include <hip/hip_bf16.h>

#define BATCH 2
#define SEQ   2048
#define HID   2048
#define NH    16
#define NKV   8
#define HD    128

typedef __bf16 bf16;
typedef bf16  bf16x8  __attribute__((ext_vector_type(8)));
typedef bf16  bf16x4  __attribute__((ext_vector_type(4)));
typedef float floatx4 __attribute__((ext_vector_type(4)));

typedef __attribute__((address_space(3))) void lds_void;
typedef const __attribute__((address_space(1))) void gmem_void;

__device__ inline void async16(const void* g, void* l) {
    __builtin_amdgcn_global_load_lds((gmem_void*)g, (lds_void*)l, 16, 0, 0);
}

// workspace layout constants (elements)
#define XN  8388608u
#define QWN 4194304u
#define KWN 2097152u
#define VWN 2097152u
#define OWN 4194304u

// ---------------------------------------------------------------------------
// Fused f32 -> bf16 convert for x + all four weights in ONE launch.
// dst regions are contiguous in ws: [xb | qwb | kwb | vwb | owb].
// 2048 elems per block; region chosen by block range (wave-uniform).
// ---------------------------------------------------------------------------
__global__ __launch_bounds__(256) void cvt_all(bf16* __restrict__ dst,
                                               const float* __restrict__ x,
                                               const float* __restrict__ qw,
                                               const float* __restrict__ kw,
                                               const float* __restrict__ vw,
                                               const float* __restrict__ ow)
{
    const int blk = blockIdx.x;
    const float* src;
    size_t off;
    if (blk < 4096)      { src = x;  off = (size_t)blk * 2048; }
    else if (blk < 6144) { src = qw; off = (size_t)(blk - 4096) * 2048; }
    else if (blk < 7168) { src = kw; off = (size_t)(blk - 6144) * 2048; }
    else if (blk < 8192) { src = vw; off = (size_t)(blk - 7168) * 2048; }
    else                 { src = ow; off = (size_t)(blk - 8192) * 2048; }

    const int t = threadIdx.x * 8;
    const float4* p = (const float4*)(src + off + t);
    float4 u0 = p[0], u1 = p[1];
    bf16x8 v;
    v[0] = (bf16)u0.x; v[1] = (bf16)u0.y; v[2] = (bf16)u0.z; v[3] = (bf16)u0.w;
    v[4] = (bf16)u1.x; v[5] = (bf16)u1.y; v[6] = (bf16)u1.z; v[7] = (bf16)u1.w;
    *(bf16x8*)(dst + (size_t)blk * 2048 + t) = v;
}

// ---------------------------------------------------------------------------
// GEMM  C = A[M,K] * W[N,K]^T, 128x128 tile, BK=32, m97 structure.
// AMODE: 0 = A f32 row-major (manual cvt stage)
//        1 = A bf16 row-major (global_load_lds)
// WMODE: 0 = W f32 (manual cvt)   1 = W bf16 (global_load_lds)
// CMODE: 0 = C f32 row-major      1 = C bf16 row-major
//        2 = C bf16 transposed [B][N][2048] (V^T)
//        3 = fused QKV epilogue: q row-major [B][S][2048] at Cp; k row-major
//            [B][S][1024] at Cp+XN; v^T [B][1024][2048] at Cp+XN+QWN.
// ---------------------------------------------------------------------------
template <int AMODE, int WMODE, int CMODE>
__global__ __launch_bounds__(256) void gemm128(void* __restrict__ Cp,
                                               const void* __restrict__ Ap,
                                               const void* __restrict__ Wp,
                                               int M, int N, int K)
{
    __shared__ bf16 As[128 * 32];
    __shared__ bf16 Ws[128 * 32];

    const int tid  = threadIdx.x;
    const int wv   = tid >> 6;
    const int lane = tid & 63;
    const int quad = lane >> 4;
    const int c    = lane & 15;

    const int m0 = blockIdx.x * 128;
    const int n0 = blockIdx.y * 128;
    const int wm = (wv >> 1) * 64;
    const int wn = (wv & 1) * 64;

    const int arow = lane >> 2;
    const int acol = (lane & 3) * 8;

    floatx4 acc[4][4] = {};

    for (int k0 = 0; k0 < K; k0 += 32) {
        if constexpr (AMODE == 0) {
            const float* A = (const float*)Ap;
            #pragma unroll
            for (int it = 0; it < 2; it++) {
                int row = it * 64 + (tid >> 2);
                int col = (tid & 3) * 8;
                const float4* p = (const float4*)(A + (size_t)(m0 + row) * K + k0 + col);
                float4 u0 = p[0], u1 = p[1];
                bf16x8 v;
                v[0] = (bf16)u0.x; v[1] = (bf16)u0.y; v[2] = (bf16)u0.z; v[3] = (bf16)u0.w;
                v[4] = (bf16)u1.x; v[5] = (bf16)u1.y; v[6] = (bf16)u1.z; v[7] = (bf16)u1.w;
                *(bf16x8*)(&As[row * 32 + col]) = v;
            }
        } else {
            const bf16* A = (const bf16*)Ap;
            #pragma unroll
            for (int ch = 0; ch < 2; ch++) {
                int row = wv * 32 + ch * 16 + arow;
                const bf16* g = A + (size_t)(m0 + row) * K + k0 + acol;
                async16(g, &As[(wv * 32 + ch * 16) * 32]);
            }
        }
        if constexpr (WMODE == 0) {
            const float* W = (const float*)Wp;
            #pragma unroll
            for (int it = 0; it < 2; it++) {
                int row = it * 64 + (tid >> 2);
                int col = (tid & 3) * 8;
                const float4* p = (const float4*)(W + (size_t)(n0 + row) * K + k0 + col);
                float4 u0 = p[0], u1 = p[1];
                bf16x8 v;
                v[0] = (bf16)u0.x; v[1] = (bf16)u0.y; v[2] = (bf16)u0.z; v[3] = (bf16)u0.w;
                v[4] = (bf16)u1.x; v[5] = (bf16)u1.y; v[6] = (bf16)u1.z; v[7] = (bf16)u1.w;
                *(bf16x8*)(&Ws[row * 32 + col]) = v;
            }
        } else {
            const bf16* W = (const bf16*)Wp;
            #pragma unroll
            for (int ch = 0; ch < 2; ch++) {
                int row = wv * 32 + ch * 16 + arow;
                const bf16* g = W + (size_t)(n0 + row) * K + k0 + acol;
                async16(g, &Ws[(wv * 32 + ch * 16) * 32]);
            }
        }
        __syncthreads();

        bf16x8 af[4], bw[4];
        #pragma unroll
        for (int i = 0; i < 4; i++) af[i] = *(const bf16x8*)(&As[(wm + i * 16 + c) * 32 + quad * 8]);
        #pragma unroll
        for (int j = 0; j < 4; j++) bw[j] = *(const bf16x8*)(&Ws[(wn + j * 16 + c) * 32 + quad * 8]);
        #pragma unroll
        for (int i = 0; i < 4; i++)
            #pragma unroll
            for (int j = 0; j < 4; j++)
                acc[i][j] = __builtin_amdgcn_mfma_f32_16x16x32_bf16(af[i], bw[j], acc[i][j], 0, 0, 0);
        __syncthreads();
    }

    // ---- epilogue.  C/D layout: col = lane&15, row = quad*4+reg ----
    if constexpr (CMODE == 0) {
        float* C = (float*)Cp;
        #pragma unroll
        for (int i = 0; i < 4; i++)
            #pragma unroll
            for (int j = 0; j < 4; j++)
                #pragma unroll
                for (int r = 0; r < 4; r++) {
                    int m = m0 + wm + i * 16 + quad * 4 + r;
                    int n = n0 + wn + j * 16 + c;
                    C[(size_t)m * N + n] = acc[i][j][r];
                }
    } else if constexpr (CMODE == 1) {
        bf16* C = (bf16*)Cp;
        #pragma unroll
        for (int i = 0; i < 4; i++)
            #pragma unroll
            for (int j = 0; j < 4; j++)
                #pragma unroll
                for (int r = 0; r < 4; r++) {
                    int m = m0 + wm + i * 16 + quad * 4 + r;
                    int n = n0 + wn + j * 16 + c;
                    C[(size_t)m * N + n] = (bf16)acc[i][j][r];
                }
    } else if constexpr (CMODE == 2) {   // V^T  [B][N][2048]
        bf16* C = (bf16*)Cp;
        const int b = m0 >> 11;
        #pragma unroll
        for (int j = 0; j < 4; j++) {
            int n = n0 + wn + j * 16 + c;
            size_t base = ((size_t)b * N + n) * 2048;
            #pragma unroll
            for (int i = 0; i < 4; i++) {
                int s0 = (m0 & 2047) + wm + i * 16 + quad * 4;
                bf16x4 v;
                #pragma unroll
                for (int r = 0; r < 4; r++) v[r] = (bf16)acc[i][j][r];
                *(bf16x4*)(&C[base + s0]) = v;
            }
        }
    } else {   // CMODE 3: fused QKV (row-major q,k; transposed v)
        bf16* Cq = (bf16*)Cp;
        if (n0 < 2048) {
            #pragma unroll
            for (int i = 0; i < 4; i++)
                #pragma unroll
                for (int j = 0; j < 4; j++)
                    #pragma unroll
                    for (int r = 0; r < 4; r++) {
                        int m = m0 + wm + i * 16 + quad * 4 + r;
                        int n = n0 + wn + j * 16 + c;
                        Cq[(size_t)m * 2048 + n] = (bf16)acc[i][j][r];
                    }
        } else if (n0 < 3072) {
            bf16* Ck = Cq + XN;
            #pragma unroll
            for (int i = 0; i < 4; i++)
                #pragma unroll
                for (int j = 0; j < 4; j++)
                    #pragma unroll
                    for (int r = 0; r < 4; r++) {
                        int m = m0 + wm + i * 16 + quad * 4 + r;
                        int n = n0 - 2048 + wn + j * 16 + c;
                        Ck[(size_t)m * 1024 + n] = (bf16)acc[i][j][r];
                    }
        } else {
            bf16* Cv = Cq + XN + QWN;
            const int b = m0 >> 11;
            #pragma unroll
            for (int j = 0; j < 4; j++) {
                int n = n0 - 3072 + wn + j * 16 + c;
                size_t base = ((size_t)b * 1024 + n) * 2048;
                #pragma unroll
                for (int i = 0; i < 4; i++) {
                    int s0 = (m0 & 2047) + wm + i * 16 + quad * 4;
                    bf16x4 v;
                    #pragma unroll
                    for (int r = 0; r < 4; r++) v[r] = (bf16)acc[i][j][r];
                    *(bf16x4*)(&Cv[base + s0]) = v;
                }
            }
        }
    }
}

// ---------------------------------------------------------------------------
// O-projection GEMM: 128x64 tile, BK=32, bf16 A/W via global_load_lds,
// f32 C row-major.  Half-width tile doubles the grid (32x32 = 1024 blocks
// = 4/CU) to fix the occupancy starvation measured at 128x128 (2/CU, 300 TF).
// ---------------------------------------------------------------------------
__global__ __launch_bounds__(256) void gemm_o64(float* __restrict__ C,
                                                const bf16* __restrict__ A,
                                                const bf16* __restrict__ W,
                                                int M, int N, int K)
{
    __shared__ bf16 As[128 * 32];
    __shared__ bf16 Ws[64 * 32];

    const int tid  = threadIdx.x;
    const int wv   = tid >> 6;
    const int lane = tid & 63;
    const int quad = lane >> 4;
    const int c    = lane & 15;

    const int m0 = blockIdx.x * 128;
    const int n0 = blockIdx.y * 64;
    const int wm = (wv >> 1) * 64;
    const int wn = (wv & 1) * 32;

    const int arow = lane >> 2;
    const int acol = (lane & 3) * 8;

    floatx4 acc[4][2] = {};

    for (int k0 = 0; k0 < K; k0 += 32) {
        #pragma unroll
        for (int ch = 0; ch < 2; ch++) {
            int row = wv * 32 + ch * 16 + arow;
            async16(A + (size_t)(m0 + row) * K + k0 + acol,
                    &As[(wv * 32 + ch * 16) * 32]);
        }
        {
            int row = wv * 16 + arow;
            async16(W + (size_t)(n0 + row) * K + k0 + acol,
                    &Ws[(wv * 16) * 32]);
        }
        __syncthreads();

        bf16x8 af[4], bw[2];
        #pragma unroll
        for (int i = 0; i < 4; i++) af[i] = *(const bf16x8*)(&As[(wm + i * 16 + c) * 32 + quad * 8]);
        #pragma unroll
        for (int j = 0; j < 2; j++) bw[j] = *(const bf16x8*)(&Ws[(wn + j * 16 + c) * 32 + quad * 8]);
        #pragma unroll
        for (int i = 0; i < 4; i++)
            #pragma unroll
            for (int j = 0; j < 2; j++)
                acc[i][j] = __builtin_amdgcn_mfma_f32_16x16x32_bf16(af[i], bw[j], acc[i][j], 0, 0, 0);
        __syncthreads();
    }

    #pragma unroll
    for (int i = 0; i < 4; i++)
        #pragma unroll
        for (int j = 0; j < 2; j++)
            #pragma unroll
            for (int r = 0; r < 4; r++) {
                int m = m0 + wm + i * 16 + quad * 4 + r;
                int n = n0 + wn + j * 16 + c;
                C[(size_t)m * N + n] = acc[i][j][r];
            }
}

// ---------------------------------------------------------------------------
// RMSNorm(D=128) + RoPE, in place on row-major bf16 q [B][S][2048] /
// k [B][S][1024].  grid = (SEQ, NH+NKV, BATCH), block = 128
// ---------------------------------------------------------------------------
__global__ __launch_bounds__(128) void norm_rope(bf16* __restrict__ q,
                                                 bf16* __restrict__ k,
                                                 const float* __restrict__ pe,
                                                 const float* __restrict__ qnw,
                                                 const float* __restrict__ knw)
{
    const int s  = blockIdx.x;
    const int hh = blockIdx.y;
    const int b  = blockIdx.z;
    const int d  = threadIdx.x;

    bf16* buf;
    const float* w;
    if (hh < NH) {
        buf = q + (size_t)(b * SEQ + s) * 2048 + hh * HD;
        w = qnw;
    } else {
        buf = k + (size_t)(b * SEQ + s) * 1024 + (hh - NH) * HD;
        w = knw;
    }

    float x = (float)buf[d];
    float ss = x * x;
    #pragma unroll
    for (int m = 32; m; m >>= 1) ss += __shfl_xor(ss, m);

    __shared__ float red[2];
    __shared__ float nv[128];
    if ((d & 63) == 0) red[d >> 6] = ss;
    __syncthreads();
    float var = (red[0] + red[1]) * (1.0f / 128.0f);
    float nx = x * rsqrtf(var + 1e-6f) * w[d];
    nv[d] = nx;
    __syncthreads();

    const float* pev = pe + ((size_t)b * SEQ + s) * HD;
    float o;
    if (d < 64) {
        o = nx * pev[d] - nv[d + 64] * pev[64 + d];
    } else {
        o = nv[d - 64] * pev[d] + nx * pev[d - 64];
    }
    buf[d] = (bf16)o;
}

// ---------------------------------------------------------------------------
// Flash attention, causal, GQA rep=2.  64q rows per block (wave owns 16),
// 64-key tiles, static-max softmax, register prefetch across the barrier.
// Row-major Q [B][S][2048], K [B][S][1024]; V^T [B][1024][2048].
// Per-CU load balance: qblk = (h&8) ? x : 31-x pairs complementary
// workloads on every CU (breadth-first dispatch stride 256 = x-period).
// ---------------------------------------------------------------------------
__global__ __launch_bounds__(256) void fattn(bf16* __restrict__ O,
                                             const bf16* __restrict__ Q,
                                             const bf16* __restrict__ Kh,
                                             const bf16* __restrict__ Vtg)
{
    const int h    = blockIdx.y;
    const int b    = blockIdx.z;
    const int qblk = (h & 8) ? (int)blockIdx.x
                             : ((int)gridDim.x - 1 - (int)blockIdx.x);
    const int kv   = h >> 1;

    const int tid  = threadIdx.x;
    const int wv   = tid >> 6;
    const int lane = tid & 63;
    const int quad = lane >> 4;
    const int c    = lane & 15;

    __shared__ bf16 Ks[64 * 136];        // [key][d]
    __shared__ bf16 Vs[128 * 72];        // [d][key]
    __shared__ bf16 Ps[4 * 16 * 72];     // per-wave P tile

    const int qw = qblk * 64 + wv * 16;

    bf16x8 qf[4];
    {
        const bf16* qp = Q + (size_t)(b * SEQ + qw + c) * 2048 + h * HD + quad * 8;
        #pragma unroll
        for (int t = 0; t < 4; t++) qf[t] = *(const bf16x8*)(qp + t * 32);
    }

    floatx4 o_acc[8] = {};
    float l_part[4] = {};

    const bf16* kbase = Kh  + (size_t)b * SEQ * 1024 + kv * HD;        // + s*1024
    const bf16* vbase = Vtg + ((size_t)b * 1024 + kv * HD) * 2048;     // + d*2048

    const int kr  = tid >> 2, ksc = (tid & 3) * 32;   // K staging: 64 rows x 128
    const int vd  = tid >> 1, vkc = (tid & 1) * 32;   // V^T staging: 128 rows x 64
    bf16* psw = &Ps[wv * 16 * 72];
    const int nkt = qblk + 1;
    const float kS = 0.08838834764831845f * 1.4426950408889634f;  // scale*log2e
    const float kB = 11.5f * 1.4426950408889634f;                 // M*log2e

    // ---- prologue: load tile 0 into registers ----
    bf16x8 kreg[4], vreg[4];
    {
        const bf16* kp = kbase + (size_t)kr * 1024 + ksc;
        const bf16* vp = vbase + (size_t)vd * 2048 + vkc;
        #pragma unroll
        for (int i = 0; i < 4; i++) kreg[i] = *(const bf16x8*)(kp + i * 8);
        #pragma unroll
        for (int i = 0; i < 4; i++) vreg[i] = *(const bf16x8*)(vp + i * 8);
    }

    for (int kt = 0; kt < nkt; kt++) {
        const int k0 = kt * 64;
        // ---- commit prefetched tile to LDS ----
        #pragma unroll
        for (int i = 0; i < 4; i++)
            *(bf16x8*)(&Ks[kr * 136 + ksc + i * 8]) = kreg[i];
        #pragma unroll
        for (int i = 0; i < 4; i++)
            *(bf16x8*)(&Vs[vd * 72 + vkc + i * 8]) = vreg[i];
        __syncthreads();

        // ---- prefetch next tile (latency covered by compute below) ----
        if (kt + 1 < nkt) {
            const bf16* kp = kbase + (size_t)(k0 + 64 + kr) * 1024 + ksc;
            const bf16* vp = vbase + (size_t)vd * 2048 + (k0 + 64) + vkc;
            #pragma unroll
            for (int i = 0; i < 4; i++) kreg[i] = *(const bf16x8*)(kp + i * 8);
            #pragma unroll
            for (int i = 0; i < 4; i++) vreg[i] = *(const bf16x8*)(vp + i * 8);
        }

        // ---- QK^T: 16 q-rows x 64 keys ----
        floatx4 sc[4] = {};
        #pragma unroll
        for (int t = 0; t < 4; t++) {
            #pragma unroll
            for (int g = 0; g < 4; g++) {
                bf16x8 kf = *(const bf16x8*)(&Ks[(g * 16 + c) * 136 + t * 32 + quad * 8]);
                sc[g] = __builtin_amdgcn_mfma_f32_16x16x32_bf16(qf[t], kf, sc[g], 0, 0, 0);
            }
        }

        // ---- static-max softmax + P store (no reductions) ----
        const bool last = (kt == nkt - 1);
        #pragma unroll
        for (int r = 0; r < 4; r++) {
            const int qrow = qw + quad * 4 + r;
            #pragma unroll
            for (int g = 0; g < 4; g++) {
                float p = exp2f(sc[g][r] * kS - kB);
                if (last && (k0 + g * 16 + c > qrow)) p = 0.0f;
                l_part[r] += p;
                psw[(quad * 4 + r) * 72 + g * 16 + c] = (bf16)p;
            }
        }
        // drain ds_writes before wave-local ds_reads (vmcnt untouched)
        asm volatile("s_waitcnt lgkmcnt(0)" ::: "memory");
        bf16x8 pf0 = *(const bf16x8*)(&psw[c * 72 + quad * 8]);
        bf16x8 pf1 = *(const bf16x8*)(&psw[c * 72 + 32 + quad * 8]);

        // ---- PV ----
        #pragma unroll
        for (int f = 0; f < 8; f++) {
            bf16x8 vf0 = *(const bf16x8*)(&Vs[(f * 16 + c) * 72 + quad * 8]);
            bf16x8 vf1 = *(const bf16x8*)(&Vs[(f * 16 + c) * 72 + 32 + quad * 8]);
            o_acc[f] = __builtin_amdgcn_mfma_f32_16x16x32_bf16(pf0, vf0, o_acc[f], 0, 0, 0);
            o_acc[f] = __builtin_amdgcn_mfma_f32_16x16x32_bf16(pf1, vf1, o_acc[f], 0, 0, 0);
        }
        __syncthreads();
    }

    // ---- epilogue: one l-reduction per row, normalize, store ----
    #pragma unroll
    for (int r = 0; r < 4; r++) {
        float l = l_part[r];
        #pragma unroll
        for (int msk = 8; msk; msk >>= 1) l += __shfl_xor(l, msk);
        const float inv = 1.0f / l;
        bf16* op = O + (size_t)(b * SEQ + qw + quad * 4 + r) * 2048 + h * HD;
        #pragma unroll
        for (int f = 0; f < 8; f++) op[f * 16 + c] = (bf16)(o_acc[f][r] * inv);
    }
}

// ---------------------------------------------------------------------------
extern "C" void kernel_launch(void* const* d_in, const int* in_sizes, int n_in,
                              void* d_out, int out_size, void* d_ws, size_t ws_size,
                              hipStream_t stream)
{
    const float* x   = (const float*)d_in[0];
    const float* pe  = (const float*)d_in[1];
    const float* qw  = (const float*)d_in[2];
    const float* kw  = (const float*)d_in[3];
    const float* vw  = (const float*)d_in[4];
    const float* ow  = (const float*)d_in[5];
    const float* qnw = (const float*)d_in[6];
    const float* knw = (const float*)d_in[7];
    float* out = (float*)d_out;

    bf16* qb = (bf16*)d_ws;          // [B][S][2048]   row-major
    bf16* kb = qb + XN;              // [B][S][1024]   row-major
    bf16* vt = kb + KWN * 2;         // [B][1024][2048] V^T
    bf16* ab = vt + VWN * 2;         // [B][S][2048]   row-major
    bf16* cvt_base = ab + XN;

    const bool fit = ws_size >= (size_t)92274688;
    const int M = BATCH * SEQ;

    if (fit) {
        bf16* xb  = cvt_base;
        bf16* qwb = xb  + XN;     // qwb|kwb|vwb contiguous => fused QKV weight [4096][2048]
        bf16* owb = qwb + QWN + KWN + VWN;

        // one launch converts x + all weights (dst regions contiguous)
        cvt_all<<<10240, 256, 0, stream>>>(xb, x, qw, kw, vw, ow);

        // fused Q|K|V projection: N = 2048+1024+1024, 1024 blocks
        gemm128<1, 1, 3><<<dim3(32, 32), 256, 0, stream>>>(qb, xb, qwb, M, 4096, 2048);

        norm_rope<<<dim3(SEQ, NH + NKV, BATCH), 128, 0, stream>>>(qb, kb, pe, qnw, knw);
        fattn<<<dim3(SEQ / 64, NH, BATCH), 256, 0, stream>>>(ab, qb, kb, vt);

        // O-projection: 128x64 tile, 1024 blocks
        gemm_o64<<<dim3(32, 32), 256, 0, stream>>>(out, ab, owb, M, 2048, 2048);
    } else {
        gemm128<0, 0, 1><<<dim3(32, 16), 256, 0, stream>>>(qb, x, qw, M, 2048, 2048);
        gemm128<0, 0, 1><<<dim3(32,  8), 256, 0, stream>>>(kb, x, kw, M, 1024, 2048);
        gemm128<0, 0, 2><<<dim3(32,  8), 256, 0, stream>>>(vt, x, vw, M, 1024, 2048);

        norm_rope<<<dim3(SEQ, NH + NKV, BATCH), 128, 0, stream>>>(qb, kb, pe, qnw, knw);
        fattn<<<dim3(SEQ / 64, NH, BATCH), 256, 0, stream>>>(ab, qb, kb, vt);

        gemm128<0, 0, 0><<<dim3(32, 16), 256, 0, stream>>>(out, ab, ow, M, 2048, 2048);
    }
}

// Round 8
// 401.858 us; speedup vs baseline: 1.4768x; 1.0488x over previous
//
#include <hip/hip_runtime.h>
#include <hip/hip_bf16.h>

#define BATCH 2
#define SEQ   2048
#define HID   2048
#define NH    16
#define NKV   8
#define HD    128

typedef __bf16 bf16;
typedef bf16  bf16x8  __attribute__((ext_vector_type(8)));
typedef bf16  bf16x4  __attribute__((ext_vector_type(4)));
typedef float floatx4 __attribute__((ext_vector_type(4)));

typedef __attribute__((address_space(3))) void lds_void;
typedef const __attribute__((address_space(1))) void gmem_void;

__device__ inline void async16(const void* g, void* l) {
    __builtin_amdgcn_global_load_lds((gmem_void*)g, (lds_void*)l, 16, 0, 0);
}

// workspace layout constants (elements)
#define XN  8388608u
#define QWN 4194304u
#define KWN 2097152u
#define VWN 2097152u
#define OWN 4194304u

// ---------------------------------------------------------------------------
// Fused f32 -> bf16 convert for x + all four weights in ONE launch.
// dst regions are contiguous in ws: [xb | qwb | kwb | vwb | owb].
// ---------------------------------------------------------------------------
__global__ __launch_bounds__(256) void cvt_all(bf16* __restrict__ dst,
                                               const float* __restrict__ x,
                                               const float* __restrict__ qw,
                                               const float* __restrict__ kw,
                                               const float* __restrict__ vw,
                                               const float* __restrict__ ow)
{
    const int blk = blockIdx.x;
    const float* src;
    size_t off;
    if (blk < 4096)      { src = x;  off = (size_t)blk * 2048; }
    else if (blk < 6144) { src = qw; off = (size_t)(blk - 4096) * 2048; }
    else if (blk < 7168) { src = kw; off = (size_t)(blk - 6144) * 2048; }
    else if (blk < 8192) { src = vw; off = (size_t)(blk - 7168) * 2048; }
    else                 { src = ow; off = (size_t)(blk - 8192) * 2048; }

    const int t = threadIdx.x * 8;
    const float4* p = (const float4*)(src + off + t);
    float4 u0 = p[0], u1 = p[1];
    bf16x8 v;
    v[0] = (bf16)u0.x; v[1] = (bf16)u0.y; v[2] = (bf16)u0.z; v[3] = (bf16)u0.w;
    v[4] = (bf16)u1.x; v[5] = (bf16)u1.y; v[6] = (bf16)u1.z; v[7] = (bf16)u1.w;
    *(bf16x8*)(dst + (size_t)blk * 2048 + t) = v;
}

// ---------------------------------------------------------------------------
// GEMM  C = A[M,K] * W[N,K]^T, 128x128 tile, BK=64 (half the barriers of
// the BK=32 m97 structure at constant staging bytes; 32 KB LDS keeps
// >=4 blocks/CU -- m132's 64 KB occupancy cliff avoided).
// AMODE: 0 = A f32 (manual cvt stage)   1 = A bf16 (global_load_lds)
// WMODE: 0 = W f32                      1 = W bf16 (global_load_lds)
// CMODE: 0 = C f32 row-major   1 = C bf16 row-major
//        2 = C bf16 transposed [B][N][2048] (V^T)
//        3 = fused QKV epilogue (q row-major | k row-major | v^T at ws offs)
// ---------------------------------------------------------------------------
template <int AMODE, int WMODE, int CMODE>
__global__ __launch_bounds__(256) void gemm128(void* __restrict__ Cp,
                                               const void* __restrict__ Ap,
                                               const void* __restrict__ Wp,
                                               int M, int N, int K)
{
    __shared__ bf16 As[128 * 64];
    __shared__ bf16 Ws[128 * 64];

    const int tid  = threadIdx.x;
    const int wv   = tid >> 6;
    const int lane = tid & 63;
    const int quad = lane >> 4;
    const int c    = lane & 15;

    const int m0 = blockIdx.x * 128;
    const int n0 = blockIdx.y * 128;
    const int wm = (wv >> 1) * 64;
    const int wn = (wv & 1) * 64;

    const int arow = lane >> 3;        // 0..7  (row within 8-row chunk)
    const int acol = (lane & 7) * 8;   // 0..56 (elem offset within 64-col row)

    floatx4 acc[4][4] = {};

    for (int k0 = 0; k0 < K; k0 += 64) {
        if constexpr (AMODE == 0) {
            const float* A = (const float*)Ap;
            #pragma unroll
            for (int it = 0; it < 4; it++) {
                int row = it * 32 + (tid >> 3);
                int col = (tid & 7) * 8;
                const float4* p = (const float4*)(A + (size_t)(m0 + row) * K + k0 + col);
                float4 u0 = p[0], u1 = p[1];
                bf16x8 v;
                v[0] = (bf16)u0.x; v[1] = (bf16)u0.y; v[2] = (bf16)u0.z; v[3] = (bf16)u0.w;
                v[4] = (bf16)u1.x; v[5] = (bf16)u1.y; v[6] = (bf16)u1.z; v[7] = (bf16)u1.w;
                *(bf16x8*)(&As[row * 64 + col]) = v;
            }
        } else {
            const bf16* A = (const bf16*)Ap;
            #pragma unroll
            for (int ch = 0; ch < 4; ch++) {
                int row = wv * 32 + ch * 8 + arow;
                async16(A + (size_t)(m0 + row) * K + k0 + acol,
                        &As[(wv * 32 + ch * 8) * 64]);
            }
        }
        if constexpr (WMODE == 0) {
            const float* W = (const float*)Wp;
            #pragma unroll
            for (int it = 0; it < 4; it++) {
                int row = it * 32 + (tid >> 3);
                int col = (tid & 7) * 8;
                const float4* p = (const float4*)(W + (size_t)(n0 + row) * K + k0 + col);
                float4 u0 = p[0], u1 = p[1];
                bf16x8 v;
                v[0] = (bf16)u0.x; v[1] = (bf16)u0.y; v[2] = (bf16)u0.z; v[3] = (bf16)u0.w;
                v[4] = (bf16)u1.x; v[5] = (bf16)u1.y; v[6] = (bf16)u1.z; v[7] = (bf16)u1.w;
                *(bf16x8*)(&Ws[row * 64 + col]) = v;
            }
        } else {
            const bf16* W = (const bf16*)Wp;
            #pragma unroll
            for (int ch = 0; ch < 4; ch++) {
                int row = wv * 32 + ch * 8 + arow;
                async16(W + (size_t)(n0 + row) * K + k0 + acol,
                        &Ws[(wv * 32 + ch * 8) * 64]);
            }
        }
        __syncthreads();

        #pragma unroll
        for (int t = 0; t < 2; t++) {
            bf16x8 af[4], bw[4];
            #pragma unroll
            for (int i = 0; i < 4; i++)
                af[i] = *(const bf16x8*)(&As[(wm + i * 16 + c) * 64 + t * 32 + quad * 8]);
            #pragma unroll
            for (int j = 0; j < 4; j++)
                bw[j] = *(const bf16x8*)(&Ws[(wn + j * 16 + c) * 64 + t * 32 + quad * 8]);
            #pragma unroll
            for (int i = 0; i < 4; i++)
                #pragma unroll
                for (int j = 0; j < 4; j++)
                    acc[i][j] = __builtin_amdgcn_mfma_f32_16x16x32_bf16(af[i], bw[j], acc[i][j], 0, 0, 0);
        }
        __syncthreads();
    }

    // ---- epilogue.  C/D layout: col = lane&15, row = quad*4+reg ----
    if constexpr (CMODE == 0) {
        float* C = (float*)Cp;
        #pragma unroll
        for (int i = 0; i < 4; i++)
            #pragma unroll
            for (int j = 0; j < 4; j++)
                #pragma unroll
                for (int r = 0; r < 4; r++) {
                    int m = m0 + wm + i * 16 + quad * 4 + r;
                    int n = n0 + wn + j * 16 + c;
                    C[(size_t)m * N + n] = acc[i][j][r];
                }
    } else if constexpr (CMODE == 1) {
        bf16* C = (bf16*)Cp;
        #pragma unroll
        for (int i = 0; i < 4; i++)
            #pragma unroll
            for (int j = 0; j < 4; j++)
                #pragma unroll
                for (int r = 0; r < 4; r++) {
                    int m = m0 + wm + i * 16 + quad * 4 + r;
                    int n = n0 + wn + j * 16 + c;
                    C[(size_t)m * N + n] = (bf16)acc[i][j][r];
                }
    } else if constexpr (CMODE == 2) {   // V^T  [B][N][2048]
        bf16* C = (bf16*)Cp;
        const int b = m0 >> 11;
        #pragma unroll
        for (int j = 0; j < 4; j++) {
            int n = n0 + wn + j * 16 + c;
            size_t base = ((size_t)b * N + n) * 2048;
            #pragma unroll
            for (int i = 0; i < 4; i++) {
                int s0 = (m0 & 2047) + wm + i * 16 + quad * 4;
                bf16x4 v;
                #pragma unroll
                for (int r = 0; r < 4; r++) v[r] = (bf16)acc[i][j][r];
                *(bf16x4*)(&C[base + s0]) = v;
            }
        }
    } else {   // CMODE 3: fused QKV (row-major q,k; transposed v)
        bf16* Cq = (bf16*)Cp;
        if (n0 < 2048) {
            #pragma unroll
            for (int i = 0; i < 4; i++)
                #pragma unroll
                for (int j = 0; j < 4; j++)
                    #pragma unroll
                    for (int r = 0; r < 4; r++) {
                        int m = m0 + wm + i * 16 + quad * 4 + r;
                        int n = n0 + wn + j * 16 + c;
                        Cq[(size_t)m * 2048 + n] = (bf16)acc[i][j][r];
                    }
        } else if (n0 < 3072) {
            bf16* Ck = Cq + XN;
            #pragma unroll
            for (int i = 0; i < 4; i++)
                #pragma unroll
                for (int j = 0; j < 4; j++)
                    #pragma unroll
                    for (int r = 0; r < 4; r++) {
                        int m = m0 + wm + i * 16 + quad * 4 + r;
                        int n = n0 - 2048 + wn + j * 16 + c;
                        Ck[(size_t)m * 1024 + n] = (bf16)acc[i][j][r];
                    }
        } else {
            bf16* Cv = Cq + XN + QWN;
            const int b = m0 >> 11;
            #pragma unroll
            for (int j = 0; j < 4; j++) {
                int n = n0 - 3072 + wn + j * 16 + c;
                size_t base = ((size_t)b * 1024 + n) * 2048;
                #pragma unroll
                for (int i = 0; i < 4; i++) {
                    int s0 = (m0 & 2047) + wm + i * 16 + quad * 4;
                    bf16x4 v;
                    #pragma unroll
                    for (int r = 0; r < 4; r++) v[r] = (bf16)acc[i][j][r];
                    *(bf16x4*)(&Cv[base + s0]) = v;
                }
            }
        }
    }
}

// ---------------------------------------------------------------------------
// O-projection GEMM: 128x64 tile, BK=64, bf16 A/W via global_load_lds,
// f32 C row-major.  1024 blocks (4/CU).
// ---------------------------------------------------------------------------
__global__ __launch_bounds__(256) void gemm_o64(float* __restrict__ C,
                                                const bf16* __restrict__ A,
                                                const bf16* __restrict__ W,
                                                int M, int N, int K)
{
    __shared__ bf16 As[128 * 64];
    __shared__ bf16 Ws[64 * 64];

    const int tid  = threadIdx.x;
    const int wv   = tid >> 6;
    const int lane = tid & 63;
    const int quad = lane >> 4;
    const int c    = lane & 15;

    const int m0 = blockIdx.x * 128;
    const int n0 = blockIdx.y * 64;
    const int wm = (wv >> 1) * 64;
    const int wn = (wv & 1) * 32;

    const int arow = lane >> 3;
    const int acol = (lane & 7) * 8;

    floatx4 acc[4][2] = {};

    for (int k0 = 0; k0 < K; k0 += 64) {
        #pragma unroll
        for (int ch = 0; ch < 4; ch++) {
            int row = wv * 32 + ch * 8 + arow;
            async16(A + (size_t)(m0 + row) * K + k0 + acol,
                    &As[(wv * 32 + ch * 8) * 64]);
        }
        #pragma unroll
        for (int ch = 0; ch < 2; ch++) {
            int row = wv * 16 + ch * 8 + arow;
            async16(W + (size_t)(n0 + row) * K + k0 + acol,
                    &Ws[(wv * 16 + ch * 8) * 64]);
        }
        __syncthreads();

        #pragma unroll
        for (int t = 0; t < 2; t++) {
            bf16x8 af[4], bw[2];
            #pragma unroll
            for (int i = 0; i < 4; i++)
                af[i] = *(const bf16x8*)(&As[(wm + i * 16 + c) * 64 + t * 32 + quad * 8]);
            #pragma unroll
            for (int j = 0; j < 2; j++)
                bw[j] = *(const bf16x8*)(&Ws[(wn + j * 16 + c) * 64 + t * 32 + quad * 8]);
            #pragma unroll
            for (int i = 0; i < 4; i++)
                #pragma unroll
                for (int j = 0; j < 2; j++)
                    acc[i][j] = __builtin_amdgcn_mfma_f32_16x16x32_bf16(af[i], bw[j], acc[i][j], 0, 0, 0);
        }
        __syncthreads();
    }

    #pragma unroll
    for (int i = 0; i < 4; i++)
        #pragma unroll
        for (int j = 0; j < 2; j++)
            #pragma unroll
            for (int r = 0; r < 4; r++) {
                int m = m0 + wm + i * 16 + quad * 4 + r;
                int n = n0 + wn + j * 16 + c;
                C[(size_t)m * N + n] = acc[i][j][r];
            }
}

// ---------------------------------------------------------------------------
// RMSNorm(D=128) + RoPE for K ONLY (q is fused into fattn's prologue).
// In place on row-major bf16 k [B][S][1024].  grid = (SEQ, NKV, BATCH).
// ---------------------------------------------------------------------------
__global__ __launch_bounds__(128) void norm_rope_k(bf16* __restrict__ k,
                                                   const float* __restrict__ pe,
                                                   const float* __restrict__ knw)
{
    const int s  = blockIdx.x;
    const int hh = blockIdx.y;
    const int b  = blockIdx.z;
    const int d  = threadIdx.x;

    bf16* buf = k + (size_t)(b * SEQ + s) * 1024 + hh * HD;

    float x = (float)buf[d];
    float ss = x * x;
    #pragma unroll
    for (int m = 32; m; m >>= 1) ss += __shfl_xor(ss, m);

    __shared__ float red[2];
    __shared__ float nv[128];
    if ((d & 63) == 0) red[d >> 6] = ss;
    __syncthreads();
    float var = (red[0] + red[1]) * (1.0f / 128.0f);
    float nx = x * rsqrtf(var + 1e-6f) * knw[d];
    nv[d] = nx;
    __syncthreads();

    const float* pev = pe + ((size_t)b * SEQ + s) * HD;
    float o;
    if (d < 64) {
        o = nx * pev[d] - nv[d + 64] * pev[64 + d];
    } else {
        o = nv[d - 64] * pev[d] + nx * pev[d - 64];
    }
    buf[d] = (bf16)o;
}

// ---------------------------------------------------------------------------
// Flash attention, causal, GQA rep=2.  64q rows per block (wave owns 16),
// 64-key tiles, static-max softmax, register prefetch across the barrier.
// q RMSNorm+RoPE fused into the prologue (q rows are block-private; RoPE
// pairs d,d+64 live in the same lane at fragment indices t,t+2).
// Row-major Q(raw) [B][S][2048], K(normed) [B][S][1024]; V^T [B][1024][2048].
// qblk = (h&8) ? x : 31-x pairs complementary workloads per CU.
// ---------------------------------------------------------------------------
__global__ __launch_bounds__(256) void fattn(bf16* __restrict__ O,
                                             const bf16* __restrict__ Q,
                                             const bf16* __restrict__ Kh,
                                             const bf16* __restrict__ Vtg,
                                             const float* __restrict__ pe,
                                             const float* __restrict__ qnw)
{
    const int h    = blockIdx.y;
    const int b    = blockIdx.z;
    const int qblk = (h & 8) ? (int)blockIdx.x
                             : ((int)gridDim.x - 1 - (int)blockIdx.x);
    const int kv   = h >> 1;

    const int tid  = threadIdx.x;
    const int wv   = tid >> 6;
    const int lane = tid & 63;
    const int quad = lane >> 4;
    const int c    = lane & 15;

    __shared__ bf16 Ks[64 * 136];        // [key][d]
    __shared__ bf16 Vs[128 * 72];        // [d][key]
    __shared__ bf16 Ps[4 * 16 * 72];     // per-wave P tile

    const int qw = qblk * 64 + wv * 16;

    // ---- prologue: load raw q row, RMSNorm + RoPE in registers ----
    bf16x8 qf[4];
    {
        const bf16* qp = Q + (size_t)(b * SEQ + qw + c) * 2048 + h * HD + quad * 8;
        float qv[4][8];
        float ss = 0.0f;
        #pragma unroll
        for (int t = 0; t < 4; t++) {
            bf16x8 raw = *(const bf16x8*)(qp + t * 32);
            #pragma unroll
            for (int j = 0; j < 8; j++) { qv[t][j] = (float)raw[j]; ss += qv[t][j] * qv[t][j]; }
        }
        // lanes c, c+16, c+32, c+48 hold the same q row
        ss += __shfl_xor(ss, 16);
        ss += __shfl_xor(ss, 32);
        const float inv = rsqrtf(ss * (1.0f / 128.0f) + 1e-6f);
        const float* pev = pe + (size_t)(b * SEQ + qw + c) * HD + quad * 8;
        float nx[4][8], pv[4][8];
        #pragma unroll
        for (int t = 0; t < 4; t++)
            #pragma unroll
            for (int j = 0; j < 8; j++) {
                pv[t][j] = pev[t * 32 + j];
                nx[t][j] = qv[t][j] * inv * qnw[t * 32 + quad * 8 + j];
            }
        #pragma unroll
        for (int t = 0; t < 2; t++)
            #pragma unroll
            for (int j = 0; j < 8; j++) {
                qf[t][j]     = (bf16)(nx[t][j] * pv[t][j]     - nx[t + 2][j] * pv[t + 2][j]);
                qf[t + 2][j] = (bf16)(nx[t][j] * pv[t + 2][j] + nx[t + 2][j] * pv[t][j]);
            }
    }

    floatx4 o_acc[8] = {};
    float l_part[4] = {};

    const bf16* kbase = Kh  + (size_t)b * SEQ * 1024 + kv * HD;        // + s*1024
    const bf16* vbase = Vtg + ((size_t)b * 1024 + kv * HD) * 2048;     // + d*2048

    const int kr  = tid >> 2, ksc = (tid & 3) * 32;   // K staging: 64 rows x 128
    const int vd  = tid >> 1, vkc = (tid & 1) * 32;   // V^T staging: 128 rows x 64
    bf16* psw = &Ps[wv * 16 * 72];
    const int nkt = qblk + 1;
    const float kS = 0.08838834764831845f * 1.4426950408889634f;  // scale*log2e
    const float kB = 11.5f * 1.4426950408889634f;                 // M*log2e

    // ---- load tile 0 into registers ----
    bf16x8 kreg[4], vreg[4];
    {
        const bf16* kp = kbase + (size_t)kr * 1024 + ksc;
        const bf16* vp = vbase + (size_t)vd * 2048 + vkc;
        #pragma unroll
        for (int i = 0; i < 4; i++) kreg[i] = *(const bf16x8*)(kp + i * 8);
        #pragma unroll
        for (int i = 0; i < 4; i++) vreg[i] = *(const bf16x8*)(vp + i * 8);
    }

    for (int kt = 0; kt < nkt; kt++) {
        const int k0 = kt * 64;
        // ---- commit prefetched tile to LDS ----
        #pragma unroll
        for (int i = 0; i < 4; i++)
            *(bf16x8*)(&Ks[kr * 136 + ksc + i * 8]) = kreg[i];
        #pragma unroll
        for (int i = 0; i < 4; i++)
            *(bf16x8*)(&Vs[vd * 72 + vkc + i * 8]) = vreg[i];
        __syncthreads();

        // ---- prefetch next tile (latency covered by compute below) ----
        if (kt + 1 < nkt) {
            const bf16* kp = kbase + (size_t)(k0 + 64 + kr) * 1024 + ksc;
            const bf16* vp = vbase + (size_t)vd * 2048 + (k0 + 64) + vkc;
            #pragma unroll
            for (int i = 0; i < 4; i++) kreg[i] = *(const bf16x8*)(kp + i * 8);
            #pragma unroll
            for (int i = 0; i < 4; i++) vreg[i] = *(const bf16x8*)(vp + i * 8);
        }

        // ---- QK^T: 16 q-rows x 64 keys ----
        floatx4 sc[4] = {};
        #pragma unroll
        for (int t = 0; t < 4; t++) {
            #pragma unroll
            for (int g = 0; g < 4; g++) {
                bf16x8 kf = *(const bf16x8*)(&Ks[(g * 16 + c) * 136 + t * 32 + quad * 8]);
                sc[g] = __builtin_amdgcn_mfma_f32_16x16x32_bf16(qf[t], kf, sc[g], 0, 0, 0);
            }
        }

        // ---- static-max softmax + P store (no reductions) ----
        const bool last = (kt == nkt - 1);
        #pragma unroll
        for (int r = 0; r < 4; r++) {
            const int qrow = qw + quad * 4 + r;
            #pragma unroll
            for (int g = 0; g < 4; g++) {
                float p = exp2f(sc[g][r] * kS - kB);
                if (last && (k0 + g * 16 + c > qrow)) p = 0.0f;
                l_part[r] += p;
                psw[(quad * 4 + r) * 72 + g * 16 + c] = (bf16)p;
            }
        }
        // drain ds_writes before wave-local ds_reads (vmcnt untouched)
        asm volatile("s_waitcnt lgkmcnt(0)" ::: "memory");
        bf16x8 pf0 = *(const bf16x8*)(&psw[c * 72 + quad * 8]);
        bf16x8 pf1 = *(const bf16x8*)(&psw[c * 72 + 32 + quad * 8]);

        // ---- PV ----
        #pragma unroll
        for (int f = 0; f < 8; f++) {
            bf16x8 vf0 = *(const bf16x8*)(&Vs[(f * 16 + c) * 72 + quad * 8]);
            bf16x8 vf1 = *(const bf16x8*)(&Vs[(f * 16 + c) * 72 + 32 + quad * 8]);
            o_acc[f] = __builtin_amdgcn_mfma_f32_16x16x32_bf16(pf0, vf0, o_acc[f], 0, 0, 0);
            o_acc[f] = __builtin_amdgcn_mfma_f32_16x16x32_bf16(pf1, vf1, o_acc[f], 0, 0, 0);
        }
        __syncthreads();
    }

    // ---- epilogue: one l-reduction per row, normalize, store ----
    #pragma unroll
    for (int r = 0; r < 4; r++) {
        float l = l_part[r];
        #pragma unroll
        for (int msk = 8; msk; msk >>= 1) l += __shfl_xor(l, msk);
        const float inv = 1.0f / l;
        bf16* op = O + (size_t)(b * SEQ + qw + quad * 4 + r) * 2048 + h * HD;
        #pragma unroll
        for (int f = 0; f < 8; f++) op[f * 16 + c] = (bf16)(o_acc[f][r] * inv);
    }
}

// ---------------------------------------------------------------------------
extern "C" void kernel_launch(void* const* d_in, const int* in_sizes, int n_in,
                              void* d_out, int out_size, void* d_ws, size_t ws_size,
                              hipStream_t stream)
{
    const float* x   = (const float*)d_in[0];
    const float* pe  = (const float*)d_in[1];
    const float* qw  = (const float*)d_in[2];
    const float* kw  = (const float*)d_in[3];
    const float* vw  = (const float*)d_in[4];
    const float* ow  = (const float*)d_in[5];
    const float* qnw = (const float*)d_in[6];
    const float* knw = (const float*)d_in[7];
    float* out = (float*)d_out;

    bf16* qb = (bf16*)d_ws;          // [B][S][2048]   row-major (raw q)
    bf16* kb = qb + XN;              // [B][S][1024]   row-major
    bf16* vt = kb + KWN * 2;         // [B][1024][2048] V^T
    bf16* ab = vt + VWN * 2;         // [B][S][2048]   row-major
    bf16* cvt_base = ab + XN;

    const bool fit = ws_size >= (size_t)92274688;
    const int M = BATCH * SEQ;

    if (fit) {
        bf16* xb  = cvt_base;
        bf16* qwb = xb  + XN;     // qwb|kwb|vwb contiguous => fused QKV weight [4096][2048]
        bf16* owb = qwb + QWN + KWN + VWN;

        cvt_all<<<10240, 256, 0, stream>>>(xb, x, qw, kw, vw, ow);

        // fused Q|K|V projection: N = 2048+1024+1024, 1024 blocks
        gemm128<1, 1, 3><<<dim3(32, 32), 256, 0, stream>>>(qb, xb, qwb, M, 4096, 2048);

        norm_rope_k<<<dim3(SEQ, NKV, BATCH), 128, 0, stream>>>(kb, pe, knw);
        fattn<<<dim3(SEQ / 64, NH, BATCH), 256, 0, stream>>>(ab, qb, kb, vt, pe, qnw);

        gemm_o64<<<dim3(32, 32), 256, 0, stream>>>(out, ab, owb, M, 2048, 2048);
    } else {
        gemm128<0, 0, 1><<<dim3(32, 16), 256, 0, stream>>>(qb, x, qw, M, 2048, 2048);
        gemm128<0, 0, 1><<<dim3(32,  8), 256, 0, stream>>>(kb, x, kw, M, 1024, 2048);
        gemm128<0, 0, 2><<<dim3(32,  8), 256, 0, stream>>>(vt, x, vw, M, 1024, 2048);

        norm_rope_k<<<dim3(SEQ, NKV, BATCH), 128, 0, stream>>>(kb, pe, knw);
        fattn<<<dim3(SEQ / 64, NH, BATCH), 256, 0, stream>>>(ab, qb, kb, vt, pe, qnw);

        gemm128<0, 0, 0><<<dim3(32, 16), 256, 0, stream>>>(out, ab, ow, M, 2048, 2048);
    }
}